// Round 14
// baseline (592.709 us; speedup 1.0000x reference)
//
#include <hip/hip_runtime.h>
#include <math.h>

#define BB 4
#define LL 1024
#define DIN 64
#define DD 512
#define HH 8
#define DH 64
#define NLAYER 3
#define DFF 2048
#define FEAT 530
#define FEATP 576
#define MM 4096

typedef float f32x4 __attribute__((ext_vector_type(4)));
typedef short s16x8 __attribute__((ext_vector_type(8)));

__device__ __forceinline__ unsigned short f2bf(float f) {
    unsigned int u = __float_as_uint(f);
    u += 0x7fffu + ((u >> 16) & 1u);
    return (unsigned short)(u >> 16);
}
__device__ __forceinline__ float bf2f(unsigned short u) {
    return __uint_as_float(((unsigned int)u) << 16);
}
__device__ __forceinline__ float gelu_exact(float x) {
    return 0.5f * x * (1.0f + erff(x * 0.7071067811865475f));
}
__device__ __forceinline__ float wave_reduce_sum(float v) {
    #pragma unroll
    for (int o = 32; o; o >>= 1) v += __shfl_down(v, o);
    return v;
}
__device__ __forceinline__ void gload16(const unsigned short* g, unsigned short* l) {
    __builtin_amdgcn_global_load_lds(
        (const __attribute__((address_space(1))) unsigned int*)g,
        (__attribute__((address_space(3))) unsigned int*)l, 16, 0, 0);
}

// ------------- fused prep: all weight f32->bf16 converts + cpe pad -------------
__global__ __launch_bounds__(256) void prep_kernel(
    const float* __restrict__ x, const float* __restrict__ inproj_w,
    const float* __restrict__ outproj_w, const float* __restrict__ ff_w1,
    const float* __restrict__ ff_w2, const float* __restrict__ in_w,
    const float* __restrict__ cpe_w,
    unsigned short* __restrict__ x_bf, unsigned short* __restrict__ w_inproj,
    unsigned short* __restrict__ w_outproj, unsigned short* __restrict__ w_ff1,
    unsigned short* __restrict__ w_ff2, unsigned short* __restrict__ w_in,
    unsigned short* __restrict__ w_cpe)
{
    const int N0 = MM * DIN;
    const int N1 = N0 + 3 * 1536 * 512;
    const int N2 = N1 + 3 * 512 * 512;
    const int N3 = N2 + 3 * 2048 * 512;
    const int N4 = N3 + 3 * 512 * 2048;
    const int N5 = N4 + 512 * 64;
    const int N6 = N5 + 512 * FEATP;
    for (int i = blockIdx.x * 256 + threadIdx.x; i < N6; i += gridDim.x * 256) {
        if (i < N0)      x_bf[i]          = f2bf(x[i]);
        else if (i < N1) w_inproj[i - N0] = f2bf(inproj_w[i - N0]);
        else if (i < N2) w_outproj[i - N1]= f2bf(outproj_w[i - N1]);
        else if (i < N3) w_ff1[i - N2]    = f2bf(ff_w1[i - N2]);
        else if (i < N4) w_ff2[i - N3]    = f2bf(ff_w2[i - N3]);
        else if (i < N5) w_in[i - N4]     = f2bf(in_w[i - N4]);
        else {
            int j = i - N5; int r = j / FEATP, c = j - r * FEATP;
            w_cpe[j] = (c < FEAT) ? f2bf(cpe_w[(size_t)r * FEAT + c]) : 0;
        }
    }
}

// ---------------- build Z[M][576] bf16 + sink row (fused) ----------------
__global__ __launch_bounds__(256) void build_z_kernel(
    const float* __restrict__ c_local, const float* __restrict__ c_sink,
    const int* __restrict__ lengths,
    const float* __restrict__ beta_p, const float* __restrict__ floor_p,
    const float* __restrict__ gamma_p,
    unsigned short* __restrict__ Z, float* __restrict__ srow)
{
    int row = blockIdx.x;
    int b = row >> 10, l = row & 1023;
    int t = threadIdx.x;
    unsigned short* zr = Z + (size_t)row * FEATP;
    for (int d = t; d < DD; d += 256) {
        int i = d >> 1;
        float dv = expf((float)(2 * i) * (-0.017988946135618352f)); // -ln(1e4)/512
        float ang = (float)l * dv;
        zr[d] = f2bf((d & 1) ? cosf(ang) : sinf(ang));
    }
    if (t < 64) {
        float cl = c_local[(size_t)b * LL + l]; cl = fminf(fmaxf(cl, 0.f), 1.f);
        float cs = c_sink [(size_t)b * LL + l]; cs = fminf(fmaxf(cs, 0.f), 1.f);
        float v = 0.f;
        if (t == 0) v = cl;
        else if (t == 1) v = cs;
        else if (t < 10)  { float c = (float)(t - 2) * (1.0f / 7.0f);  float df = (cl - c) / 0.200001f; v = expf(-0.5f * df * df); }
        else if (t < 18)  { float c = (float)(t - 10) * (1.0f / 7.0f); float df = (cs - c) / 0.200001f; v = expf(-0.5f * df * df); }
        zr[512 + t] = (t < 18) ? f2bf(v) : 0;
        if (t == 32) {
            float sv = (*beta_p) * ((*floor_p) + (1.f - (*floor_p)) * powf(cs + 1e-6f, *gamma_p));
            srow[row] = (l < lengths[b]) ? sv : 0.f;
        }
    }
}

// ---------------- delay feature encoder: e[B,D] ----------------
__global__ __launch_bounds__(512) void delay_kernel(
    const float* __restrict__ delay, const float* __restrict__ w1, const float* __restrict__ b1,
    const float* __restrict__ w2, const float* __restrict__ b2,
    const float* __restrict__ lng, const float* __restrict__ lnb,
    float* __restrict__ e)
{
    int b = blockIdx.x;
    int t = threadIdx.x;
    __shared__ float g1[DD];
    __shared__ float red[16];
    float t1 = delay[b] * w1[t] + b1[t];
    g1[t] = gelu_exact(t1);
    __syncthreads();
    const float* wr = w2 + (size_t)t * DD;
    float s = b2[t];
    for (int j = 0; j < DD; j += 4) {
        float4 w4 = *(const float4*)(wr + j);
        s += w4.x * g1[j] + w4.y * g1[j+1] + w4.z * g1[j+2] + w4.w * g1[j+3];
    }
    float rs = wave_reduce_sum(s);
    float rss = wave_reduce_sum(s * s);
    int lane = t & 63, w = t >> 6;
    if (lane == 0) { red[w] = rs; red[8 + w] = rss; }
    __syncthreads();
    float mean = 0.f, msq = 0.f;
    #pragma unroll
    for (int i = 0; i < 8; ++i) { mean += red[i]; msq += red[8 + i]; }
    mean *= (1.0f / DD); msq *= (1.0f / DD);
    float rstd = rsqrtf(msq - mean * mean + 1e-5f);
    e[(size_t)b * DD + t] = (s - mean) * rstd * lng[t] + lnb[t];
}

// ---- templated MFMA GEMM, BK=64, double-buffered LDS (T3-min 2-phase) ----
template<int BM, int BN, int FM, int FN, int WGN, int MODE>
__global__ __launch_bounds__(256) void gemm_t(
    const unsigned short* __restrict__ A, const unsigned short* __restrict__ W,
    const float* __restrict__ bias, const float* __restrict__ resid,
    float* __restrict__ outf, unsigned short* __restrict__ outb,
    int M, int N, int K)
{
    __shared__ __align__(16) unsigned short As[2][BM * 64];
    __shared__ __align__(16) unsigned short Ws[2][BN * 64];
    int bm = blockIdx.y * BM, bn = blockIdx.x * BN;
    int t = threadIdx.x;
    int lane = t & 63, wid = t >> 6;
    int wr = wid / WGN, wc = wid % WGN;
    int l15 = lane & 15, lg = lane >> 4;
    int sr = lane >> 3;
    int sc = ((lane & 7) ^ sr) * 8;
    int ph0 = (lg ^ (l15 & 7)) * 8;
    int ph1 = ((lg + 4) ^ (l15 & 7)) * 8;

    f32x4 acc[FM][FN] = {};
    int nk = K >> 6;

    auto stage = [&](int buf, int ks) {
        int kb = ks * 64;
        #pragma unroll
        for (int i = 0; i < BM / 32; ++i) {
            int row = wid * (BM / 4) + i * 8 + sr;
            gload16(A + (size_t)(bm + row) * K + kb + sc, &As[buf][(wid * (BM / 4) + i * 8) * 64]);
        }
        #pragma unroll
        for (int i = 0; i < BN / 32; ++i) {
            int row = wid * (BN / 4) + i * 8 + sr;
            gload16(W + (size_t)(bn + row) * K + kb + sc, &Ws[buf][(wid * (BN / 4) + i * 8) * 64]);
        }
    };

    stage(0, 0);
    __syncthreads();

    int cur = 0;
    for (int ks = 0; ks < nk; ++ks) {
        if (ks + 1 < nk) stage(cur ^ 1, ks + 1);
        s16x8 af0[FM], af1[FM], wf0[FN], wf1[FN];
        #pragma unroll
        for (int mi = 0; mi < FM; ++mi) {
            int row = wr * FM * 16 + mi * 16 + l15;
            af0[mi] = *(const s16x8*)&As[cur][row * 64 + ph0];
            af1[mi] = *(const s16x8*)&As[cur][row * 64 + ph1];
        }
        #pragma unroll
        for (int ni = 0; ni < FN; ++ni) {
            int row = wc * FN * 16 + ni * 16 + l15;
            wf0[ni] = *(const s16x8*)&Ws[cur][row * 64 + ph0];
            wf1[ni] = *(const s16x8*)&Ws[cur][row * 64 + ph1];
        }
        #pragma unroll
        for (int mi = 0; mi < FM; ++mi)
            #pragma unroll
            for (int ni = 0; ni < FN; ++ni) {
                acc[mi][ni] = __builtin_amdgcn_mfma_f32_16x16x32_bf16(af0[mi], wf0[ni], acc[mi][ni], 0, 0, 0);
                acc[mi][ni] = __builtin_amdgcn_mfma_f32_16x16x32_bf16(af1[mi], wf1[ni], acc[mi][ni], 0, 0, 0);
            }
        __syncthreads();
        cur ^= 1;
    }

    int rbase = (lane >> 4) * 4;
    #pragma unroll
    for (int mi = 0; mi < FM; ++mi) {
        #pragma unroll
        for (int ni = 0; ni < FN; ++ni) {
            int n = bn + wc * FN * 16 + ni * 16 + l15;
            float bzc = (MODE == 4) ? 0.f : bias[n];
            #pragma unroll
            for (int r2 = 0; r2 < 4; ++r2) {
                int m = bm + wr * FM * 16 + mi * 16 + rbase + r2;
                float v = acc[mi][ni][r2] + ((MODE == 4) ? bias[m] : bzc);
                size_t o = (size_t)m * N + n;
                if (MODE == 0)      outf[o] = v;
                else if (MODE == 1) outb[o] = f2bf(v);
                else if (MODE == 2) outf[o] = v + resid[o];
                else if (MODE == 3) outb[o] = f2bf(gelu_exact(v));
                else                outb[o] = f2bf(v);
            }
        }
    }
}

// ------------- MFMA flash attention: QBLK=32, 2 waves, grid 1024 (4 chains/CU) -------------
// qk: [B*L][1024] bf16 (Q at 0, K at 512). Vt: [512][4096] bf16 = V^T per (h,d) row.
#define SK 72
#define SPB 72
__global__ __launch_bounds__(128) void attn_mfma(
    const unsigned short* __restrict__ qk, const unsigned short* __restrict__ Vt,
    const float* __restrict__ c_local, const float* __restrict__ srow,
    const int* __restrict__ lengths,
    const float* __restrict__ alpha_p,
    unsigned short* __restrict__ o)
{
    __shared__ __align__(16) unsigned short Ks[64 * SK];
    __shared__ __align__(16) unsigned short Vts[64 * SK];
    __shared__ __align__(16) unsigned short Psb[32 * SPB];

    int id = blockIdx.x;
    int q0 = (id & 31) * 32;
    int hh = (id >> 5) & 7;
    int b  = id >> 8;

    int t  = threadIdx.x;
    int lane = t & 63, w = t >> 6;          // w in {0,1}
    int l15 = lane & 15, lg = lane >> 4;
    int len = lengths[b];
    int nt = (len + 63) >> 6;
    int ktlo = (q0 > 0 ? q0 - 1 : 0) >> 6;  // slow-tile window for neighbor bias
    int kthi = (q0 + 32) >> 6;
    bool sink_blk = (q0 == 0);
    const float alpha = *alpha_p;

    // Q fragments, pre-scaled by 1/8 (exact: exponent shift)
    const unsigned short* qrow = qk + (size_t)(b * LL + q0 + w * 16 + l15) * 1024 + hh * DH;
    s16x8 qf0 = *(const s16x8*)(qrow + lg * 8);
    s16x8 qf1 = *(const s16x8*)(qrow + 32 + lg * 8);
    #pragma unroll
    for (int j = 0; j < 8; ++j) {
        qf0[j] = (short)f2bf(bf2f((unsigned short)qf0[j]) * 0.125f);
        qf1[j] = (short)f2bf(bf2f((unsigned short)qf1[j]) * 0.125f);
    }

    float cm1[4], cp1[4];
    #pragma unroll
    for (int r2 = 0; r2 < 4; ++r2) {
        int qi = q0 + w * 16 + lg * 4 + r2;
        cm1[r2] = 0.f; cp1[r2] = 0.f;
        if (qi >= 1 && qi < len) {
            int src = (qi == 1 || qi == LL - 1) ? qi : qi - 1;
            cm1[r2] = alpha * c_local[(size_t)b * LL + src];
        }
        if (qi + 1 < LL && qi < len)
            cp1[r2] = alpha * c_local[(size_t)b * LL + qi + 1];
    }
    bool need_sink = (sink_blk && w == 0 && lg == 0);

    float m_run[4], l_run[4];
    f32x4 accO[4] = {};
    #pragma unroll
    for (int r2 = 0; r2 < 4; ++r2) { m_run[r2] = -1e30f; l_run[r2] = 0.f; }

    int sr = t >> 3, sc8 = (t & 7) * 8;     // 16 rows per pass at 128 threads
    const unsigned short* kbase = qk + (size_t)(b * LL) * 1024 + 512 + hh * DH;
    const unsigned short* vbase = Vt + (size_t)(hh * DH) * MM + b * LL;

    uint4 pk[4], pv[4];
    #pragma unroll
    for (int u = 0; u < 4; ++u) {
        pk[u] = *(const uint4*)(kbase + (size_t)(sr + u * 16) * 1024 + sc8);
        pv[u] = *(const uint4*)(vbase + (size_t)(sr + u * 16) * MM + sc8);
    }

    for (int kt = 0; kt < nt; ++kt) {
        int k0 = kt * 64;
        #pragma unroll
        for (int u = 0; u < 4; ++u) {
            *(uint4*)&Ks[(sr + u * 16) * SK + sc8]  = pk[u];
            *(uint4*)&Vts[(sr + u * 16) * SK + sc8] = pv[u];
        }
        if (kt + 1 < nt) {
            int kn = k0 + 64;
            #pragma unroll
            for (int u = 0; u < 4; ++u) {
                pk[u] = *(const uint4*)(kbase + (size_t)(kn + sr + u * 16) * 1024 + sc8);
                pv[u] = *(const uint4*)(vbase + (size_t)(sr + u * 16) * MM + kn + sc8);
            }
        }
        __syncthreads();

        // S = Q K^T (pre-scaled)
        f32x4 accS[4] = {};
        #pragma unroll
        for (int ct = 0; ct < 4; ++ct) {
            s16x8 kf0 = *(const s16x8*)&Ks[(ct * 16 + l15) * SK + lg * 8];
            s16x8 kf1 = *(const s16x8*)&Ks[(ct * 16 + l15) * SK + 32 + lg * 8];
            accS[ct] = __builtin_amdgcn_mfma_f32_16x16x32_bf16(qf0, kf0, accS[ct], 0, 0, 0);
            accS[ct] = __builtin_amdgcn_mfma_f32_16x16x32_bf16(qf1, kf1, accS[ct], 0, 0, 0);
        }

        float m4[4] = { -1e30f, -1e30f, -1e30f, -1e30f };
        bool slow = sink_blk || (kt >= ktlo && kt <= kthi) || (k0 + 64 > len);
        if (!slow) {
            #pragma unroll
            for (int ct = 0; ct < 4; ++ct)
                #pragma unroll
                for (int r2 = 0; r2 < 4; ++r2)
                    m4[r2] = fmaxf(m4[r2], accS[ct][r2]);
        } else if (k0 + 64 <= len) {
            #pragma unroll
            for (int ct = 0; ct < 4; ++ct) {
                int k = k0 + ct * 16 + l15;
                float sink_ct = need_sink ? srow[(size_t)b * LL + k] : 0.f;
                #pragma unroll
                for (int r2 = 0; r2 < 4; ++r2) {
                    int qi = q0 + w * 16 + lg * 4 + r2;
                    float v = accS[ct][r2];
                    if (k == qi - 1) v += cm1[r2];
                    else if (k == qi + 1) v += cp1[r2];
                    if (r2 == 0) v += sink_ct;
                    accS[ct][r2] = v;
                    m4[r2] = fmaxf(m4[r2], v);
                }
            }
        } else {
            #pragma unroll
            for (int ct = 0; ct < 4; ++ct) {
                int k = k0 + ct * 16 + l15;
                bool maskk = (k >= len);
                float sink_ct = need_sink ? srow[(size_t)b * LL + k] : 0.f;
                #pragma unroll
                for (int r2 = 0; r2 < 4; ++r2) {
                    int qi = q0 + w * 16 + lg * 4 + r2;
                    float v = accS[ct][r2];
                    if (k == qi - 1) v += cm1[r2];
                    else if (k == qi + 1 && !maskk) v += cp1[r2];
                    if (r2 == 0) v += sink_ct;
                    if (maskk) v -= 10000.f;
                    accS[ct][r2] = v;
                    m4[r2] = fmaxf(m4[r2], v);
                }
            }
        }

        #pragma unroll
        for (int r2 = 0; r2 < 4; ++r2) {
            #pragma unroll
            for (int msk = 1; msk < 16; msk <<= 1) m4[r2] = fmaxf(m4[r2], __shfl_xor(m4[r2], msk));
            float mnew = fmaxf(m_run[r2], m4[r2]);
            float scl = __expf(m_run[r2] - mnew);
            m_run[r2] = mnew;
            float rowsum = 0.f;
            #pragma unroll
            for (int ct = 0; ct < 4; ++ct) {
                float p = __expf(accS[ct][r2] - mnew);
                rowsum += p;
                Psb[(w * 16 + lg * 4 + r2) * SPB + ct * 16 + l15] = f2bf(p);
            }
            #pragma unroll
            for (int msk = 1; msk < 16; msk <<= 1) rowsum += __shfl_xor(rowsum, msk);
            l_run[r2] = l_run[r2] * scl + rowsum;
            #pragma unroll
            for (int dt = 0; dt < 4; ++dt) accO[dt][r2] *= scl;
        }

        // O += P @ V (wave-local P rows; Psb needs no barrier)
        #pragma unroll
        for (int kk = 0; kk < 2; ++kk) {
            s16x8 pf = *(const s16x8*)&Psb[(w * 16 + l15) * SPB + kk * 32 + lg * 8];
            #pragma unroll
            for (int dt = 0; dt < 4; ++dt) {
                s16x8 vf = *(const s16x8*)&Vts[(dt * 16 + l15) * SK + kk * 32 + lg * 8];
                accO[dt] = __builtin_amdgcn_mfma_f32_16x16x32_bf16(pf, vf, accO[dt], 0, 0, 0);
            }
        }
        __syncthreads();
    }

    #pragma unroll
    for (int r2 = 0; r2 < 4; ++r2) {
        float inv = 1.f / l_run[r2];
        int qi = q0 + w * 16 + lg * 4 + r2;
        #pragma unroll
        for (int dt = 0; dt < 4; ++dt)
            o[(size_t)(b * LL + qi) * DD + hh * DH + dt * 16 + l15] = f2bf(accO[dt][r2] * inv);
    }
}

// ------ embed epilogue: h += e + mask?0:gain*LN(cpe_pre) ------
__global__ __launch_bounds__(256) void embed_ep_kernel(
    const float* __restrict__ cpe_pre, const float* __restrict__ e,
    const int* __restrict__ lengths,
    const float* __restrict__ cpe_g, const float* __restrict__ cpe_lb,
    const float* __restrict__ gain_p, float* __restrict__ h)
{
    int row = blockIdx.x;
    int b = row >> 10, l = row & 1023;
    int t = threadIdx.x;
    __shared__ float red[16];
    const float* cp = cpe_pre + (size_t)row * DD;
    float v0 = cp[t], v1 = cp[t + 256];
    float s = v0 + v1, ss = v0 * v0 + v1 * v1;
    float rs = wave_reduce_sum(s), rss = wave_reduce_sum(ss);
    int lane = t & 63, w = t >> 6;
    if (lane == 0) { red[w] = rs; red[8 + w] = rss; }
    __syncthreads();
    float mean = 0.f, msq = 0.f;
    #pragma unroll
    for (int i = 0; i < 4; ++i) { mean += red[i]; msq += red[8 + i]; }
    mean *= (1.0f / DD); msq *= (1.0f / DD);
    float rstd = rsqrtf(msq - mean * mean + 1e-5f);
    bool maskp = (l >= lengths[b]);
    float gain = *gain_p;
    float pe0 = maskp ? 0.f : gain * ((v0 - mean) * rstd * cpe_g[t] + cpe_lb[t]);
    float pe1 = maskp ? 0.f : gain * ((v1 - mean) * rstd * cpe_g[t + 256] + cpe_lb[t + 256]);
    h[(size_t)row * DD + t]       += e[(size_t)b * DD + t] + pe0;
    h[(size_t)row * DD + t + 256] += e[(size_t)b * DD + t + 256] + pe1;
}

// ---------------- LayerNorm f32 out (final) ----------------
__global__ __launch_bounds__(256) void ln_kernel(
    const float* __restrict__ in, float* __restrict__ out,
    const float* __restrict__ g, const float* __restrict__ bta)
{
    int row = blockIdx.x; int t = threadIdx.x;
    __shared__ float red[16];
    const float* xr = in + (size_t)row * DD;
    float2 v = ((const float2*)xr)[t];
    float s = v.x + v.y, ss = v.x * v.x + v.y * v.y;
    float rs = wave_reduce_sum(s), rss = wave_reduce_sum(ss);
    int lane = t & 63, w = t >> 6;
    if (lane == 0) { red[w] = rs; red[8 + w] = rss; }
    __syncthreads();
    float mean = 0.f, msq = 0.f;
    #pragma unroll
    for (int i = 0; i < 4; ++i) { mean += red[i]; msq += red[8 + i]; }
    mean *= (1.0f / DD); msq *= (1.0f / DD);
    float rstd = rsqrtf(msq - mean * mean + 1e-5f);
    float2 gg = ((const float2*)g)[t], bb = ((const float2*)bta)[t];
    float2 o;
    o.x = (v.x - mean) * rstd * gg.x + bb.x;
    o.y = (v.y - mean) * rstd * gg.y + bb.y;
    ((float2*)(out + (size_t)row * DD))[t] = o;
}

// ---------------- LayerNorm bf16 out ----------------
__global__ __launch_bounds__(256) void ln_bf16_kernel(
    const float* __restrict__ in, unsigned short* __restrict__ out,
    const float* __restrict__ g, const float* __restrict__ bta)
{
    int row = blockIdx.x; int t = threadIdx.x;
    __shared__ float red[16];
    const float* xr = in + (size_t)row * DD;
    float2 v = ((const float2*)xr)[t];
    float s = v.x + v.y, ss = v.x * v.x + v.y * v.y;
    float rs = wave_reduce_sum(s), rss = wave_reduce_sum(ss);
    int lane = t & 63, w = t >> 6;
    if (lane == 0) { red[w] = rs; red[8 + w] = rss; }
    __syncthreads();
    float mean = 0.f, msq = 0.f;
    #pragma unroll
    for (int i = 0; i < 4; ++i) { mean += red[i]; msq += red[8 + i]; }
    mean *= (1.0f / DD); msq *= (1.0f / DD);
    float rstd = rsqrtf(msq - mean * mean + 1e-5f);
    float2 gg = ((const float2*)g)[t], bb = ((const float2*)bta)[t];
    ushort2 o;
    o.x = f2bf((v.x - mean) * rstd * gg.x + bb.x);
    o.y = f2bf((v.y - mean) * rstd * gg.y + bb.y);
    ((ushort2*)(out + (size_t)row * DD))[t] = o;
}

extern "C" void kernel_launch(void* const* d_in, const int* in_sizes, int n_in,
                              void* d_out, int out_size, void* d_ws, size_t ws_size,
                              hipStream_t stream)
{
    const float* x          = (const float*)d_in[0];
    const int*   lengths    = (const int*)  d_in[1];
    const float* input_delay= (const float*)d_in[2];
    const float* c_local    = (const float*)d_in[3];
    const float* c_sink     = (const float*)d_in[4];
    const float* in_w       = (const float*)d_in[5];
    const float* in_b       = (const float*)d_in[6];
    const float* de_w1      = (const float*)d_in[7];
    const float* de_b1      = (const float*)d_in[8];
    const float* de_w2      = (const float*)d_in[9];
    const float* de_b2      = (const float*)d_in[10];
    const float* de_ln_g    = (const float*)d_in[11];
    const float* de_ln_b    = (const float*)d_in[12];
    const float* cpe_w      = (const float*)d_in[13];
    const float* cpe_b      = (const float*)d_in[14];
    const float* cpe_ln_g   = (const float*)d_in[15];
    const float* cpe_ln_b   = (const float*)d_in[16];
    const float* gain       = (const float*)d_in[17];
    const float* alpha      = (const float*)d_in[18];
    const float* beta       = (const float*)d_in[19];
    const float* floorp     = (const float*)d_in[20];
    const float* gammap     = (const float*)d_in[21];
    const float* inproj_w   = (const float*)d_in[22];
    const float* inproj_b   = (const float*)d_in[23];
    const float* outproj_w  = (const float*)d_in[24];
    const float* outproj_b  = (const float*)d_in[25];
    const float* ln1_g      = (const float*)d_in[26];
    const float* ln1_b      = (const float*)d_in[27];
    const float* ln2_g      = (const float*)d_in[28];
    const float* ln2_b      = (const float*)d_in[29];
    const float* ff_w1      = (const float*)d_in[30];
    const float* ff_b1      = (const float*)d_in[31];
    const float* ff_w2      = (const float*)d_in[32];
    const float* ff_b2      = (const float*)d_in[33];
    const float* out_ln_g   = (const float*)d_in[34];
    const float* out_ln_b   = (const float*)d_in[35];

    char* base = (char*)d_ws;
    float* h            = (float*)base;                               // 8 MB
    unsigned short* act1 = (unsigned short*)(base + 8u*1024*1024);    // 4 MB
    char* bigb          = base + 12u*1024*1024;                       // 16 MB shared region
    unsigned short* qkb  = (unsigned short*)bigb;                     // 8 MB (attn phase: Q,K)
    unsigned short* vtb  = (unsigned short*)(bigb + 12u*1024*1024);   // 4 MB (attn phase: V^T [512][4096])
    unsigned short* ffb  = (unsigned short*)bigb;                     // 16 MB (FF phase)
    unsigned short* Zb   = (unsigned short*)bigb;                     // 4.7 MB (embed phase)
    unsigned short* x_bf = (unsigned short*)(bigb + 5u*1024*1024);    // 0.5 MB
    float* cpe_pre       = (float*)(bigb + 8u*1024*1024);             // 8 MB
    unsigned short* w_inproj  = (unsigned short*)(base + 28u*1024*1024);
    unsigned short* w_outproj = w_inproj  + (size_t)3*1536*512;
    unsigned short* w_ff1     = w_outproj + (size_t)3*512*512;
    unsigned short* w_ff2     = w_ff1     + (size_t)3*2048*512;
    unsigned short* w_in      = w_ff2     + (size_t)3*512*2048;
    unsigned short* w_cpe     = w_in      + (size_t)512*64;
    float* e                  = (float*)(w_cpe + (size_t)512*FEATP);
    float* srow               = e + (size_t)BB*DD;

    prep_kernel<<<2048, 256, 0, stream>>>(x, inproj_w, outproj_w, ff_w1, ff_w2, in_w, cpe_w,
                                          x_bf, w_inproj, w_outproj, w_ff1, w_ff2, w_in, w_cpe);
    delay_kernel<<<BB, 512, 0, stream>>>(input_delay, de_w1, de_b1, de_w2, de_b2, de_ln_g, de_ln_b, e);
    build_z_kernel<<<MM, 256, 0, stream>>>(c_local, c_sink, lengths, beta, floorp, gammap, Zb, srow);

    gemm_t<64, 64, 2, 2, 2, 0><<<dim3(DD / 64, MM / 64), 256, 0, stream>>>(
        x_bf, w_in, in_b, nullptr, h, nullptr, MM, DD, DIN);
    gemm_t<64, 64, 2, 2, 2, 0><<<dim3(DD / 64, MM / 64), 256, 0, stream>>>(
        Zb, w_cpe, cpe_b, nullptr, cpe_pre, nullptr, MM, DD, FEATP);
    embed_ep_kernel<<<MM, 256, 0, stream>>>(cpe_pre, e, lengths, cpe_ln_g, cpe_ln_b, gain, h);

    for (int i = 0; i < NLAYER; ++i) {
        const unsigned short* wqk = w_inproj + (size_t)i * 1536 * 512;          // Q,K rows [0,1024)
        const unsigned short* wv  = wqk + (size_t)1024 * 512;                   // V rows [1024,1536)
        ln_bf16_kernel<<<MM, 256, 0, stream>>>(h, act1, ln1_g + (size_t)i * DD, ln1_b + (size_t)i * DD);
        gemm_t<64, 128, 2, 4, 2, 1><<<dim3(1024 / 128, MM / 64), 256, 0, stream>>>(
            act1, wqk, inproj_b + (size_t)i * 1536, nullptr, nullptr, qkb, MM, 1024, DD);
        gemm_t<64, 64, 2, 2, 2, 4><<<dim3(MM / 64, DD / 64), 256, 0, stream>>>(
            wv, act1, inproj_b + (size_t)i * 1536 + 1024, nullptr, nullptr, vtb, DD, MM, DD);
        attn_mfma<<<1024, 128, 0, stream>>>(qkb, vtb, c_local, srow, lengths, alpha, act1);
        gemm_t<64, 64, 2, 2, 2, 2><<<dim3(DD / 64, MM / 64), 256, 0, stream>>>(
            act1, w_outproj + (size_t)i * 512 * 512, outproj_b + (size_t)i * DD,
            h, h, nullptr, MM, DD, DD);
        ln_bf16_kernel<<<MM, 256, 0, stream>>>(h, act1, ln2_g + (size_t)i * DD, ln2_b + (size_t)i * DD);
        gemm_t<128, 128, 4, 4, 2, 3><<<dim3(DFF / 128, MM / 128), 256, 0, stream>>>(
            act1, w_ff1 + (size_t)i * 2048 * 512, ff_b1 + (size_t)i * DFF,
            nullptr, nullptr, ffb, MM, DFF, DD);
        gemm_t<64, 64, 2, 2, 2, 2><<<dim3(DD / 64, MM / 64), 256, 0, stream>>>(
            ffb, w_ff2 + (size_t)i * 512 * 2048, ff_b2 + (size_t)i * DD,
            h, h, nullptr, MM, DD, DFF);
    }
    ln_kernel<<<MM, 256, 0, stream>>>(h, (float*)d_out, out_ln_g, out_ln_b);
}

// Round 15
// 443.503 us; speedup vs baseline: 1.3364x; 1.3364x over previous
//
#include <hip/hip_runtime.h>
#include <math.h>

#define BB 4
#define LL 1024
#define DIN 64
#define DD 512
#define HH 8
#define DH 64
#define NLAYER 3
#define DFF 2048
#define FEAT 530
#define FEATP 576
#define MM 4096

typedef float f32x4 __attribute__((ext_vector_type(4)));
typedef short s16x8 __attribute__((ext_vector_type(8)));

__device__ __forceinline__ unsigned short f2bf(float f) {
    unsigned int u = __float_as_uint(f);
    u += 0x7fffu + ((u >> 16) & 1u);
    return (unsigned short)(u >> 16);
}
__device__ __forceinline__ float bf2f(unsigned short u) {
    return __uint_as_float(((unsigned int)u) << 16);
}
__device__ __forceinline__ float gelu_exact(float x) {
    return 0.5f * x * (1.0f + erff(x * 0.7071067811865475f));
}
__device__ __forceinline__ float wave_reduce_sum(float v) {
    #pragma unroll
    for (int o = 32; o; o >>= 1) v += __shfl_down(v, o);
    return v;
}
__device__ __forceinline__ void gload16(const unsigned short* g, unsigned short* l) {
    __builtin_amdgcn_global_load_lds(
        (const __attribute__((address_space(1))) unsigned int*)g,
        (__attribute__((address_space(3))) unsigned int*)l, 16, 0, 0);
}

// ------------- fused prep: all weight f32->bf16 converts + cpe pad -------------
__global__ __launch_bounds__(256) void prep_kernel(
    const float* __restrict__ x, const float* __restrict__ inproj_w,
    const float* __restrict__ outproj_w, const float* __restrict__ ff_w1,
    const float* __restrict__ ff_w2, const float* __restrict__ in_w,
    const float* __restrict__ cpe_w,
    unsigned short* __restrict__ x_bf, unsigned short* __restrict__ w_inproj,
    unsigned short* __restrict__ w_outproj, unsigned short* __restrict__ w_ff1,
    unsigned short* __restrict__ w_ff2, unsigned short* __restrict__ w_in,
    unsigned short* __restrict__ w_cpe)
{
    const int N0 = MM * DIN;
    const int N1 = N0 + 3 * 1536 * 512;
    const int N2 = N1 + 3 * 512 * 512;
    const int N3 = N2 + 3 * 2048 * 512;
    const int N4 = N3 + 3 * 512 * 2048;
    const int N5 = N4 + 512 * 64;
    const int N6 = N5 + 512 * FEATP;
    for (int i = blockIdx.x * 256 + threadIdx.x; i < N6; i += gridDim.x * 256) {
        if (i < N0)      x_bf[i]          = f2bf(x[i]);
        else if (i < N1) w_inproj[i - N0] = f2bf(inproj_w[i - N0]);
        else if (i < N2) w_outproj[i - N1]= f2bf(outproj_w[i - N1]);
        else if (i < N3) w_ff1[i - N2]    = f2bf(ff_w1[i - N2]);
        else if (i < N4) w_ff2[i - N3]    = f2bf(ff_w2[i - N3]);
        else if (i < N5) w_in[i - N4]     = f2bf(in_w[i - N4]);
        else {
            int j = i - N5; int r = j / FEATP, c = j - r * FEATP;
            w_cpe[j] = (c < FEAT) ? f2bf(cpe_w[(size_t)r * FEAT + c]) : 0;
        }
    }
}

// ---------------- build Z[M][576] bf16 + sink row (fused) ----------------
__global__ __launch_bounds__(256) void build_z_kernel(
    const float* __restrict__ c_local, const float* __restrict__ c_sink,
    const int* __restrict__ lengths,
    const float* __restrict__ beta_p, const float* __restrict__ floor_p,
    const float* __restrict__ gamma_p,
    unsigned short* __restrict__ Z, float* __restrict__ srow)
{
    int row = blockIdx.x;
    int b = row >> 10, l = row & 1023;
    int t = threadIdx.x;
    unsigned short* zr = Z + (size_t)row * FEATP;
    for (int d = t; d < DD; d += 256) {
        int i = d >> 1;
        float dv = expf((float)(2 * i) * (-0.017988946135618352f)); // -ln(1e4)/512
        float ang = (float)l * dv;
        zr[d] = f2bf((d & 1) ? cosf(ang) : sinf(ang));
    }
    if (t < 64) {
        float cl = c_local[(size_t)b * LL + l]; cl = fminf(fmaxf(cl, 0.f), 1.f);
        float cs = c_sink [(size_t)b * LL + l]; cs = fminf(fmaxf(cs, 0.f), 1.f);
        float v = 0.f;
        if (t == 0) v = cl;
        else if (t == 1) v = cs;
        else if (t < 10)  { float c = (float)(t - 2) * (1.0f / 7.0f);  float df = (cl - c) / 0.200001f; v = expf(-0.5f * df * df); }
        else if (t < 18)  { float c = (float)(t - 10) * (1.0f / 7.0f); float df = (cs - c) / 0.200001f; v = expf(-0.5f * df * df); }
        zr[512 + t] = (t < 18) ? f2bf(v) : 0;
        if (t == 32) {
            float sv = (*beta_p) * ((*floor_p) + (1.f - (*floor_p)) * powf(cs + 1e-6f, *gamma_p));
            srow[row] = (l < lengths[b]) ? sv : 0.f;
        }
    }
}

// ---------------- delay feature encoder: e[B,D] ----------------
__global__ __launch_bounds__(512) void delay_kernel(
    const float* __restrict__ delay, const float* __restrict__ w1, const float* __restrict__ b1,
    const float* __restrict__ w2, const float* __restrict__ b2,
    const float* __restrict__ lng, const float* __restrict__ lnb,
    float* __restrict__ e)
{
    int b = blockIdx.x;
    int t = threadIdx.x;
    __shared__ float g1[DD];
    __shared__ float red[16];
    float t1 = delay[b] * w1[t] + b1[t];
    g1[t] = gelu_exact(t1);
    __syncthreads();
    const float* wr = w2 + (size_t)t * DD;
    float s = b2[t];
    for (int j = 0; j < DD; j += 4) {
        float4 w4 = *(const float4*)(wr + j);
        s += w4.x * g1[j] + w4.y * g1[j+1] + w4.z * g1[j+2] + w4.w * g1[j+3];
    }
    float rs = wave_reduce_sum(s);
    float rss = wave_reduce_sum(s * s);
    int lane = t & 63, w = t >> 6;
    if (lane == 0) { red[w] = rs; red[8 + w] = rss; }
    __syncthreads();
    float mean = 0.f, msq = 0.f;
    #pragma unroll
    for (int i = 0; i < 8; ++i) { mean += red[i]; msq += red[8 + i]; }
    mean *= (1.0f / DD); msq *= (1.0f / DD);
    float rstd = rsqrtf(msq - mean * mean + 1e-5f);
    e[(size_t)b * DD + t] = (s - mean) * rstd * lng[t] + lnb[t];
}

// ---- templated MFMA GEMM, BK=64, double-buffered LDS (T3-min 2-phase) ----
template<int BM, int BN, int FM, int FN, int WGN, int MODE>
__global__ __launch_bounds__(256) void gemm_t(
    const unsigned short* __restrict__ A, const unsigned short* __restrict__ W,
    const float* __restrict__ bias, const float* __restrict__ resid,
    float* __restrict__ outf, unsigned short* __restrict__ outb,
    int M, int N, int K)
{
    __shared__ __align__(16) unsigned short As[2][BM * 64];
    __shared__ __align__(16) unsigned short Ws[2][BN * 64];
    int bm = blockIdx.y * BM, bn = blockIdx.x * BN;
    int t = threadIdx.x;
    int lane = t & 63, wid = t >> 6;
    int wr = wid / WGN, wc = wid % WGN;
    int l15 = lane & 15, lg = lane >> 4;
    int sr = lane >> 3;
    int sc = ((lane & 7) ^ sr) * 8;
    int ph0 = (lg ^ (l15 & 7)) * 8;
    int ph1 = ((lg + 4) ^ (l15 & 7)) * 8;

    f32x4 acc[FM][FN] = {};
    int nk = K >> 6;

    auto stage = [&](int buf, int ks) {
        int kb = ks * 64;
        #pragma unroll
        for (int i = 0; i < BM / 32; ++i) {
            int row = wid * (BM / 4) + i * 8 + sr;
            gload16(A + (size_t)(bm + row) * K + kb + sc, &As[buf][(wid * (BM / 4) + i * 8) * 64]);
        }
        #pragma unroll
        for (int i = 0; i < BN / 32; ++i) {
            int row = wid * (BN / 4) + i * 8 + sr;
            gload16(W + (size_t)(bn + row) * K + kb + sc, &Ws[buf][(wid * (BN / 4) + i * 8) * 64]);
        }
    };

    stage(0, 0);
    __syncthreads();

    int cur = 0;
    for (int ks = 0; ks < nk; ++ks) {
        if (ks + 1 < nk) stage(cur ^ 1, ks + 1);
        s16x8 af0[FM], af1[FM], wf0[FN], wf1[FN];
        #pragma unroll
        for (int mi = 0; mi < FM; ++mi) {
            int row = wr * FM * 16 + mi * 16 + l15;
            af0[mi] = *(const s16x8*)&As[cur][row * 64 + ph0];
            af1[mi] = *(const s16x8*)&As[cur][row * 64 + ph1];
        }
        #pragma unroll
        for (int ni = 0; ni < FN; ++ni) {
            int row = wc * FN * 16 + ni * 16 + l15;
            wf0[ni] = *(const s16x8*)&Ws[cur][row * 64 + ph0];
            wf1[ni] = *(const s16x8*)&Ws[cur][row * 64 + ph1];
        }
        __builtin_amdgcn_s_setprio(1);
        #pragma unroll
        for (int mi = 0; mi < FM; ++mi)
            #pragma unroll
            for (int ni = 0; ni < FN; ++ni) {
                acc[mi][ni] = __builtin_amdgcn_mfma_f32_16x16x32_bf16(af0[mi], wf0[ni], acc[mi][ni], 0, 0, 0);
                acc[mi][ni] = __builtin_amdgcn_mfma_f32_16x16x32_bf16(af1[mi], wf1[ni], acc[mi][ni], 0, 0, 0);
            }
        __builtin_amdgcn_s_setprio(0);
        __syncthreads();
        cur ^= 1;
    }

    int rbase = (lane >> 4) * 4;
    #pragma unroll
    for (int mi = 0; mi < FM; ++mi) {
        #pragma unroll
        for (int ni = 0; ni < FN; ++ni) {
            int n = bn + wc * FN * 16 + ni * 16 + l15;
            float bzc = (MODE == 4) ? 0.f : bias[n];
            #pragma unroll
            for (int r2 = 0; r2 < 4; ++r2) {
                int m = bm + wr * FM * 16 + mi * 16 + rbase + r2;
                float v = acc[mi][ni][r2] + ((MODE == 4) ? bias[m] : bzc);
                size_t o = (size_t)m * N + n;
                if (MODE == 0)      outf[o] = v;
                else if (MODE == 1) outb[o] = f2bf(v);
                else if (MODE == 2) outf[o] = v + resid[o];
                else if (MODE == 3) outb[o] = f2bf(gelu_exact(v));
                else                outb[o] = f2bf(v);
            }
        }
    }
}

// ------------- MFMA flash attention: natural block order (XCD-balanced), dbuf K/V -------------
// qk: [B*L][1024] bf16 (Q at 0, K at 512). Vt: [512][4096] bf16 = V^T per (h,d) row.
#define SK 72
#define SPB 72
__global__ __launch_bounds__(256) void attn_mfma(
    const unsigned short* __restrict__ qk, const unsigned short* __restrict__ Vt,
    const float* __restrict__ c_local, const float* __restrict__ srow,
    const int* __restrict__ lengths,
    const float* __restrict__ alpha_p,
    unsigned short* __restrict__ o)
{
    __shared__ __align__(16) unsigned short Ks[2][64 * SK];
    __shared__ __align__(16) unsigned short Vts[2][64 * SK];
    __shared__ __align__(16) unsigned short Psb[64 * SPB];

    int id = blockIdx.x;
    int q0 = (id & 15) * 64;
    int hh = (id >> 4) & 7;
    int b  = id >> 7;

    int t  = threadIdx.x;
    int lane = t & 63, w = t >> 6;
    int l15 = lane & 15, lg = lane >> 4;
    int len = lengths[b];
    int nt = (len + 63) >> 6;
    int kt0 = q0 >> 6;
    bool sink_blk = (q0 == 0);
    const float alpha = *alpha_p;

    const unsigned short* qrow = qk + (size_t)(b * LL + q0 + w * 16 + l15) * 1024 + hh * DH;
    s16x8 qf0 = *(const s16x8*)(qrow + lg * 8);
    s16x8 qf1 = *(const s16x8*)(qrow + 32 + lg * 8);
    #pragma unroll
    for (int j = 0; j < 8; ++j) {
        qf0[j] = (short)f2bf(bf2f((unsigned short)qf0[j]) * 0.125f);
        qf1[j] = (short)f2bf(bf2f((unsigned short)qf1[j]) * 0.125f);
    }

    float cm1[4], cp1[4];
    #pragma unroll
    for (int r2 = 0; r2 < 4; ++r2) {
        int qi = q0 + w * 16 + lg * 4 + r2;
        cm1[r2] = 0.f; cp1[r2] = 0.f;
        if (qi >= 1 && qi < len) {
            int src = (qi == 1 || qi == LL - 1) ? qi : qi - 1;
            cm1[r2] = alpha * c_local[(size_t)b * LL + src];
        }
        if (qi + 1 < LL && qi < len)
            cp1[r2] = alpha * c_local[(size_t)b * LL + qi + 1];
    }
    bool need_sink = (sink_blk && w == 0 && lg == 0);

    float m_run[4], l_run[4];
    f32x4 accO[4] = {};
    #pragma unroll
    for (int r2 = 0; r2 < 4; ++r2) { m_run[r2] = -1e30f; l_run[r2] = 0.f; }

    int sr = t >> 3, sc8 = (t & 7) * 8;
    const unsigned short* kbase = qk + (size_t)(b * LL) * 1024 + 512 + hh * DH;
    const unsigned short* vbase = Vt + (size_t)(hh * DH) * MM + b * LL;

    uint4 pk0 = *(const uint4*)(kbase + (size_t)sr * 1024 + sc8);
    uint4 pk1 = *(const uint4*)(kbase + (size_t)(sr + 32) * 1024 + sc8);
    uint4 pv0 = *(const uint4*)(vbase + (size_t)sr * MM + sc8);
    uint4 pv1 = *(const uint4*)(vbase + (size_t)(sr + 32) * MM + sc8);
    *(uint4*)&Ks[0][sr * SK + sc8]         = pk0;
    *(uint4*)&Ks[0][(sr + 32) * SK + sc8]  = pk1;
    *(uint4*)&Vts[0][sr * SK + sc8]        = pv0;
    *(uint4*)&Vts[0][(sr + 32) * SK + sc8] = pv1;
    __syncthreads();

    int cur = 0;
    for (int kt = 0; kt < nt; ++kt) {
        int k0 = kt * 64;
        bool pre = (kt + 1 < nt);
        if (pre) {
            int kn = k0 + 64;
            pk0 = *(const uint4*)(kbase + (size_t)(kn + sr) * 1024 + sc8);
            pk1 = *(const uint4*)(kbase + (size_t)(kn + sr + 32) * 1024 + sc8);
            pv0 = *(const uint4*)(vbase + (size_t)sr * MM + kn + sc8);
            pv1 = *(const uint4*)(vbase + (size_t)(sr + 32) * MM + kn + sc8);
        }

        f32x4 accS[4] = {};
        #pragma unroll
        for (int ct = 0; ct < 4; ++ct) {
            s16x8 kf0 = *(const s16x8*)&Ks[cur][(ct * 16 + l15) * SK + lg * 8];
            s16x8 kf1 = *(const s16x8*)&Ks[cur][(ct * 16 + l15) * SK + 32 + lg * 8];
            accS[ct] = __builtin_amdgcn_mfma_f32_16x16x32_bf16(qf0, kf0, accS[ct], 0, 0, 0);
            accS[ct] = __builtin_amdgcn_mfma_f32_16x16x32_bf16(qf1, kf1, accS[ct], 0, 0, 0);
        }

        float m4[4] = { -1e30f, -1e30f, -1e30f, -1e30f };
        bool slow = sink_blk || (kt >= kt0 - 1 && kt <= kt0 + 1) || (k0 + 64 > len);
        if (!slow) {
            #pragma unroll
            for (int ct = 0; ct < 4; ++ct)
                #pragma unroll
                for (int r2 = 0; r2 < 4; ++r2)
                    m4[r2] = fmaxf(m4[r2], accS[ct][r2]);
        } else if (k0 + 64 <= len) {
            #pragma unroll
            for (int ct = 0; ct < 4; ++ct) {
                int k = k0 + ct * 16 + l15;
                float sink_ct = need_sink ? srow[(size_t)b * LL + k] : 0.f;
                #pragma unroll
                for (int r2 = 0; r2 < 4; ++r2) {
                    int qi = q0 + w * 16 + lg * 4 + r2;
                    float v = accS[ct][r2];
                    if (k == qi - 1) v += cm1[r2];
                    else if (k == qi + 1) v += cp1[r2];
                    if (r2 == 0) v += sink_ct;
                    accS[ct][r2] = v;
                    m4[r2] = fmaxf(m4[r2], v);
                }
            }
        } else {
            #pragma unroll
            for (int ct = 0; ct < 4; ++ct) {
                int k = k0 + ct * 16 + l15;
                bool maskk = (k >= len);
                float sink_ct = need_sink ? srow[(size_t)b * LL + k] : 0.f;
                #pragma unroll
                for (int r2 = 0; r2 < 4; ++r2) {
                    int qi = q0 + w * 16 + lg * 4 + r2;
                    float v = accS[ct][r2];
                    if (k == qi - 1) v += cm1[r2];
                    else if (k == qi + 1 && !maskk) v += cp1[r2];
                    if (r2 == 0) v += sink_ct;
                    if (maskk) v -= 10000.f;
                    accS[ct][r2] = v;
                    m4[r2] = fmaxf(m4[r2], v);
                }
            }
        }

        #pragma unroll
        for (int r2 = 0; r2 < 4; ++r2) {
            #pragma unroll
            for (int msk = 1; msk < 16; msk <<= 1) m4[r2] = fmaxf(m4[r2], __shfl_xor(m4[r2], msk));
            float mnew = fmaxf(m_run[r2], m4[r2]);
            float scl = __expf(m_run[r2] - mnew);
            m_run[r2] = mnew;
            float rowsum = 0.f;
            #pragma unroll
            for (int ct = 0; ct < 4; ++ct) {
                float p = __expf(accS[ct][r2] - mnew);
                rowsum += p;
                Psb[(w * 16 + lg * 4 + r2) * SPB + ct * 16 + l15] = f2bf(p);
            }
            #pragma unroll
            for (int msk = 1; msk < 16; msk <<= 1) rowsum += __shfl_xor(rowsum, msk);
            l_run[r2] = l_run[r2] * scl + rowsum;
            #pragma unroll
            for (int dt = 0; dt < 4; ++dt) accO[dt][r2] *= scl;
        }

        #pragma unroll
        for (int kk = 0; kk < 2; ++kk) {
            s16x8 pf = *(const s16x8*)&Psb[(w * 16 + l15) * SPB + kk * 32 + lg * 8];
            #pragma unroll
            for (int dt = 0; dt < 4; ++dt) {
                s16x8 vf = *(const s16x8*)&Vts[cur][(dt * 16 + l15) * SK + kk * 32 + lg * 8];
                accO[dt] = __builtin_amdgcn_mfma_f32_16x16x32_bf16(pf, vf, accO[dt], 0, 0, 0);
            }
        }

        if (pre) {
            int nxt = cur ^ 1;
            *(uint4*)&Ks[nxt][sr * SK + sc8]         = pk0;
            *(uint4*)&Ks[nxt][(sr + 32) * SK + sc8]  = pk1;
            *(uint4*)&Vts[nxt][sr * SK + sc8]        = pv0;
            *(uint4*)&Vts[nxt][(sr + 32) * SK + sc8] = pv1;
        }
        __syncthreads();
        cur ^= 1;
    }

    #pragma unroll
    for (int r2 = 0; r2 < 4; ++r2) {
        float inv = 1.f / l_run[r2];
        int qi = q0 + w * 16 + lg * 4 + r2;
        #pragma unroll
        for (int dt = 0; dt < 4; ++dt)
            o[(size_t)(b * LL + qi) * DD + hh * DH + dt * 16 + l15] = f2bf(accO[dt][r2] * inv);
    }
}

// ------ embed epilogue: h += e + mask?0:gain*LN(cpe_pre) ------
__global__ __launch_bounds__(256) void embed_ep_kernel(
    const float* __restrict__ cpe_pre, const float* __restrict__ e,
    const int* __restrict__ lengths,
    const float* __restrict__ cpe_g, const float* __restrict__ cpe_lb,
    const float* __restrict__ gain_p, float* __restrict__ h)
{
    int row = blockIdx.x;
    int b = row >> 10, l = row & 1023;
    int t = threadIdx.x;
    __shared__ float red[16];
    const float* cp = cpe_pre + (size_t)row * DD;
    float v0 = cp[t], v1 = cp[t + 256];
    float s = v0 + v1, ss = v0 * v0 + v1 * v1;
    float rs = wave_reduce_sum(s), rss = wave_reduce_sum(ss);
    int lane = t & 63, w = t >> 6;
    if (lane == 0) { red[w] = rs; red[8 + w] = rss; }
    __syncthreads();
    float mean = 0.f, msq = 0.f;
    #pragma unroll
    for (int i = 0; i < 4; ++i) { mean += red[i]; msq += red[8 + i]; }
    mean *= (1.0f / DD); msq *= (1.0f / DD);
    float rstd = rsqrtf(msq - mean * mean + 1e-5f);
    bool maskp = (l >= lengths[b]);
    float gain = *gain_p;
    float pe0 = maskp ? 0.f : gain * ((v0 - mean) * rstd * cpe_g[t] + cpe_lb[t]);
    float pe1 = maskp ? 0.f : gain * ((v1 - mean) * rstd * cpe_g[t + 256] + cpe_lb[t + 256]);
    h[(size_t)row * DD + t]       += e[(size_t)b * DD + t] + pe0;
    h[(size_t)row * DD + t + 256] += e[(size_t)b * DD + t + 256] + pe1;
}

// ---------------- LayerNorm f32 out (final) ----------------
__global__ __launch_bounds__(256) void ln_kernel(
    const float* __restrict__ in, float* __restrict__ out,
    const float* __restrict__ g, const float* __restrict__ bta)
{
    int row = blockIdx.x; int t = threadIdx.x;
    __shared__ float red[16];
    const float* xr = in + (size_t)row * DD;
    float2 v = ((const float2*)xr)[t];
    float s = v.x + v.y, ss = v.x * v.x + v.y * v.y;
    float rs = wave_reduce_sum(s), rss = wave_reduce_sum(ss);
    int lane = t & 63, w = t >> 6;
    if (lane == 0) { red[w] = rs; red[8 + w] = rss; }
    __syncthreads();
    float mean = 0.f, msq = 0.f;
    #pragma unroll
    for (int i = 0; i < 4; ++i) { mean += red[i]; msq += red[8 + i]; }
    mean *= (1.0f / DD); msq *= (1.0f / DD);
    float rstd = rsqrtf(msq - mean * mean + 1e-5f);
    float2 gg = ((const float2*)g)[t], bb = ((const float2*)bta)[t];
    float2 o;
    o.x = (v.x - mean) * rstd * gg.x + bb.x;
    o.y = (v.y - mean) * rstd * gg.y + bb.y;
    ((float2*)(out + (size_t)row * DD))[t] = o;
}

// ---------------- LayerNorm bf16 out ----------------
__global__ __launch_bounds__(256) void ln_bf16_kernel(
    const float* __restrict__ in, unsigned short* __restrict__ out,
    const float* __restrict__ g, const float* __restrict__ bta)
{
    int row = blockIdx.x; int t = threadIdx.x;
    __shared__ float red[16];
    const float* xr = in + (size_t)row * DD;
    float2 v = ((const float2*)xr)[t];
    float s = v.x + v.y, ss = v.x * v.x + v.y * v.y;
    float rs = wave_reduce_sum(s), rss = wave_reduce_sum(ss);
    int lane = t & 63, w = t >> 6;
    if (lane == 0) { red[w] = rs; red[8 + w] = rss; }
    __syncthreads();
    float mean = 0.f, msq = 0.f;
    #pragma unroll
    for (int i = 0; i < 4; ++i) { mean += red[i]; msq += red[8 + i]; }
    mean *= (1.0f / DD); msq *= (1.0f / DD);
    float rstd = rsqrtf(msq - mean * mean + 1e-5f);
    float2 gg = ((const float2*)g)[t], bb = ((const float2*)bta)[t];
    ushort2 o;
    o.x = f2bf((v.x - mean) * rstd * gg.x + bb.x);
    o.y = f2bf((v.y - mean) * rstd * gg.y + bb.y);
    ((ushort2*)(out + (size_t)row * DD))[t] = o;
}

extern "C" void kernel_launch(void* const* d_in, const int* in_sizes, int n_in,
                              void* d_out, int out_size, void* d_ws, size_t ws_size,
                              hipStream_t stream)
{
    const float* x          = (const float*)d_in[0];
    const int*   lengths    = (const int*)  d_in[1];
    const float* input_delay= (const float*)d_in[2];
    const float* c_local    = (const float*)d_in[3];
    const float* c_sink     = (const float*)d_in[4];
    const float* in_w       = (const float*)d_in[5];
    const float* in_b       = (const float*)d_in[6];
    const float* de_w1      = (const float*)d_in[7];
    const float* de_b1      = (const float*)d_in[8];
    const float* de_w2      = (const float*)d_in[9];
    const float* de_b2      = (const float*)d_in[10];
    const float* de_ln_g    = (const float*)d_in[11];
    const float* de_ln_b    = (const float*)d_in[12];
    const float* cpe_w      = (const float*)d_in[13];
    const float* cpe_b      = (const float*)d_in[14];
    const float* cpe_ln_g   = (const float*)d_in[15];
    const float* cpe_ln_b   = (const float*)d_in[16];
    const float* gain       = (const float*)d_in[17];
    const float* alpha      = (const float*)d_in[18];
    const float* beta       = (const float*)d_in[19];
    const float* floorp     = (const float*)d_in[20];
    const float* gammap     = (const float*)d_in[21];
    const float* inproj_w   = (const float*)d_in[22];
    const float* inproj_b   = (const float*)d_in[23];
    const float* outproj_w  = (const float*)d_in[24];
    const float* outproj_b  = (const float*)d_in[25];
    const float* ln1_g      = (const float*)d_in[26];
    const float* ln1_b      = (const float*)d_in[27];
    const float* ln2_g      = (const float*)d_in[28];
    const float* ln2_b      = (const float*)d_in[29];
    const float* ff_w1      = (const float*)d_in[30];
    const float* ff_b1      = (const float*)d_in[31];
    const float* ff_w2      = (const float*)d_in[32];
    const float* ff_b2      = (const float*)d_in[33];
    const float* out_ln_g   = (const float*)d_in[34];
    const float* out_ln_b   = (const float*)d_in[35];

    char* base = (char*)d_ws;
    float* h            = (float*)base;                               // 8 MB
    unsigned short* act1 = (unsigned short*)(base + 8u*1024*1024);    // 4 MB
    char* bigb          = base + 12u*1024*1024;                       // 16 MB shared region
    unsigned short* qkb  = (unsigned short*)bigb;                     // 8 MB (attn phase: Q,K)
    unsigned short* vtb  = (unsigned short*)(bigb + 12u*1024*1024);   // 4 MB (attn phase: V^T [512][4096])
    unsigned short* ffb  = (unsigned short*)bigb;                     // 16 MB (FF phase)
    unsigned short* Zb   = (unsigned short*)bigb;                     // 4.7 MB (embed phase)
    unsigned short* x_bf = (unsigned short*)(bigb + 5u*1024*1024);    // 0.5 MB
    float* cpe_pre       = (float*)(bigb + 8u*1024*1024);             // 8 MB
    unsigned short* w_inproj  = (unsigned short*)(base + 28u*1024*1024);
    unsigned short* w_outproj = w_inproj  + (size_t)3*1536*512;
    unsigned short* w_ff1     = w_outproj + (size_t)3*512*512;
    unsigned short* w_ff2     = w_ff1     + (size_t)3*2048*512;
    unsigned short* w_in      = w_ff2     + (size_t)3*512*2048;
    unsigned short* w_cpe     = w_in      + (size_t)512*64;
    float* e                  = (float*)(w_cpe + (size_t)512*FEATP);
    float* srow               = e + (size_t)BB*DD;

    prep_kernel<<<2048, 256, 0, stream>>>(x, inproj_w, outproj_w, ff_w1, ff_w2, in_w, cpe_w,
                                          x_bf, w_inproj, w_outproj, w_ff1, w_ff2, w_in, w_cpe);
    delay_kernel<<<BB, 512, 0, stream>>>(input_delay, de_w1, de_b1, de_w2, de_b2, de_ln_g, de_ln_b, e);
    build_z_kernel<<<MM, 256, 0, stream>>>(c_local, c_sink, lengths, beta, floorp, gammap, Zb, srow);

    gemm_t<64, 64, 2, 2, 2, 0><<<dim3(DD / 64, MM / 64), 256, 0, stream>>>(
        x_bf, w_in, in_b, nullptr, h, nullptr, MM, DD, DIN);
    gemm_t<64, 64, 2, 2, 2, 0><<<dim3(DD / 64, MM / 64), 256, 0, stream>>>(
        Zb, w_cpe, cpe_b, nullptr, cpe_pre, nullptr, MM, DD, FEATP);
    embed_ep_kernel<<<MM, 256, 0, stream>>>(cpe_pre, e, lengths, cpe_ln_g, cpe_ln_b, gain, h);

    for (int i = 0; i < NLAYER; ++i) {
        const unsigned short* wqk = w_inproj + (size_t)i * 1536 * 512;          // Q,K rows [0,1024)
        const unsigned short* wv  = wqk + (size_t)1024 * 512;                   // V rows [1024,1536)
        ln_bf16_kernel<<<MM, 256, 0, stream>>>(h, act1, ln1_g + (size_t)i * DD, ln1_b + (size_t)i * DD);
        gemm_t<64, 128, 2, 4, 2, 1><<<dim3(1024 / 128, MM / 64), 256, 0, stream>>>(
            act1, wqk, inproj_b + (size_t)i * 1536, nullptr, nullptr, qkb, MM, 1024, DD);
        gemm_t<64, 64, 2, 2, 2, 4><<<dim3(MM / 64, DD / 64), 256, 0, stream>>>(
            wv, act1, inproj_b + (size_t)i * 1536 + 1024, nullptr, nullptr, vtb, DD, MM, DD);
        attn_mfma<<<512, 256, 0, stream>>>(qkb, vtb, c_local, srow, lengths, alpha, act1);
        gemm_t<64, 64, 2, 2, 2, 2><<<dim3(DD / 64, MM / 64), 256, 0, stream>>>(
            act1, w_outproj + (size_t)i * 512 * 512, outproj_b + (size_t)i * DD,
            h, h, nullptr, MM, DD, DD);
        ln_bf16_kernel<<<MM, 256, 0, stream>>>(h, act1, ln2_g + (size_t)i * DD, ln2_b + (size_t)i * DD);
        gemm_t<128, 128, 4, 4, 2, 3><<<dim3(DFF / 128, MM / 128), 256, 0, stream>>>(
            act1, w_ff1 + (size_t)i * 2048 * 512, ff_b1 + (size_t)i * DFF,
            nullptr, nullptr, ffb, MM, DFF, DD);
        gemm_t<64, 64, 2, 2, 2, 2><<<dim3(DD / 64, MM / 64), 256, 0, stream>>>(
            ffb, w_ff2 + (size_t)i * 512 * 2048, ff_b2 + (size_t)i * DD,
            h, h, nullptr, MM, DD, DFF);
    }
    ln_kernel<<<MM, 256, 0, stream>>>(h, (float*)d_out, out_ln_g, out_ln_b);
}

// Round 16
// 438.735 us; speedup vs baseline: 1.3509x; 1.0109x over previous
//
#include <hip/hip_runtime.h>
#include <math.h>

#define BB 4
#define LL 1024
#define DIN 64
#define DD 512
#define HH 8
#define DH 64
#define NLAYER 3
#define DFF 2048
#define FEAT 530
#define FEATP 576
#define MM 4096

typedef float f32x4 __attribute__((ext_vector_type(4)));
typedef short s16x8 __attribute__((ext_vector_type(8)));

__device__ __forceinline__ unsigned short f2bf(float f) {
    unsigned int u = __float_as_uint(f);
    u += 0x7fffu + ((u >> 16) & 1u);
    return (unsigned short)(u >> 16);
}
__device__ __forceinline__ float bf2f(unsigned short u) {
    return __uint_as_float(((unsigned int)u) << 16);
}
__device__ __forceinline__ float gelu_exact(float x) {
    return 0.5f * x * (1.0f + erff(x * 0.7071067811865475f));
}
__device__ __forceinline__ float wave_reduce_sum(float v) {
    #pragma unroll
    for (int o = 32; o; o >>= 1) v += __shfl_down(v, o);
    return v;
}
__device__ __forceinline__ void gload16(const unsigned short* g, unsigned short* l) {
    __builtin_amdgcn_global_load_lds(
        (const __attribute__((address_space(1))) unsigned int*)g,
        (__attribute__((address_space(3))) unsigned int*)l, 16, 0, 0);
}

// ------------- fused prep: all weight f32->bf16 converts + cpe pad -------------
__global__ __launch_bounds__(256) void prep_kernel(
    const float* __restrict__ x, const float* __restrict__ inproj_w,
    const float* __restrict__ outproj_w, const float* __restrict__ ff_w1,
    const float* __restrict__ ff_w2, const float* __restrict__ in_w,
    const float* __restrict__ cpe_w,
    unsigned short* __restrict__ x_bf, unsigned short* __restrict__ w_inproj,
    unsigned short* __restrict__ w_outproj, unsigned short* __restrict__ w_ff1,
    unsigned short* __restrict__ w_ff2, unsigned short* __restrict__ w_in,
    unsigned short* __restrict__ w_cpe)
{
    const int N0 = MM * DIN;
    const int N1 = N0 + 3 * 1536 * 512;
    const int N2 = N1 + 3 * 512 * 512;
    const int N3 = N2 + 3 * 2048 * 512;
    const int N4 = N3 + 3 * 512 * 2048;
    const int N5 = N4 + 512 * 64;
    const int N6 = N5 + 512 * FEATP;
    for (int i = blockIdx.x * 256 + threadIdx.x; i < N6; i += gridDim.x * 256) {
        if (i < N0)      x_bf[i]          = f2bf(x[i]);
        else if (i < N1) w_inproj[i - N0] = f2bf(inproj_w[i - N0]);
        else if (i < N2) w_outproj[i - N1]= f2bf(outproj_w[i - N1]);
        else if (i < N3) w_ff1[i - N2]    = f2bf(ff_w1[i - N2]);
        else if (i < N4) w_ff2[i - N3]    = f2bf(ff_w2[i - N3]);
        else if (i < N5) w_in[i - N4]     = f2bf(in_w[i - N4]);
        else {
            int j = i - N5; int r = j / FEATP, c = j - r * FEATP;
            w_cpe[j] = (c < FEAT) ? f2bf(cpe_w[(size_t)r * FEAT + c]) : 0;
        }
    }
}

// ---------------- build Z[M][576] bf16 + sink row (fused) ----------------
__global__ __launch_bounds__(256) void build_z_kernel(
    const float* __restrict__ c_local, const float* __restrict__ c_sink,
    const int* __restrict__ lengths,
    const float* __restrict__ beta_p, const float* __restrict__ floor_p,
    const float* __restrict__ gamma_p,
    unsigned short* __restrict__ Z, float* __restrict__ srow)
{
    int row = blockIdx.x;
    int b = row >> 10, l = row & 1023;
    int t = threadIdx.x;
    unsigned short* zr = Z + (size_t)row * FEATP;
    for (int d = t; d < DD; d += 256) {
        int i = d >> 1;
        float dv = expf((float)(2 * i) * (-0.017988946135618352f)); // -ln(1e4)/512
        float ang = (float)l * dv;
        zr[d] = f2bf((d & 1) ? cosf(ang) : sinf(ang));
    }
    if (t < 64) {
        float cl = c_local[(size_t)b * LL + l]; cl = fminf(fmaxf(cl, 0.f), 1.f);
        float cs = c_sink [(size_t)b * LL + l]; cs = fminf(fmaxf(cs, 0.f), 1.f);
        float v = 0.f;
        if (t == 0) v = cl;
        else if (t == 1) v = cs;
        else if (t < 10)  { float c = (float)(t - 2) * (1.0f / 7.0f);  float df = (cl - c) / 0.200001f; v = expf(-0.5f * df * df); }
        else if (t < 18)  { float c = (float)(t - 10) * (1.0f / 7.0f); float df = (cs - c) / 0.200001f; v = expf(-0.5f * df * df); }
        zr[512 + t] = (t < 18) ? f2bf(v) : 0;
        if (t == 32) {
            float sv = (*beta_p) * ((*floor_p) + (1.f - (*floor_p)) * powf(cs + 1e-6f, *gamma_p));
            srow[row] = (l < lengths[b]) ? sv : 0.f;
        }
    }
}

// ---------------- delay feature encoder: e[B,D] ----------------
__global__ __launch_bounds__(512) void delay_kernel(
    const float* __restrict__ delay, const float* __restrict__ w1, const float* __restrict__ b1,
    const float* __restrict__ w2, const float* __restrict__ b2,
    const float* __restrict__ lng, const float* __restrict__ lnb,
    float* __restrict__ e)
{
    int b = blockIdx.x;
    int t = threadIdx.x;
    __shared__ float g1[DD];
    __shared__ float red[16];
    float t1 = delay[b] * w1[t] + b1[t];
    g1[t] = gelu_exact(t1);
    __syncthreads();
    const float* wr = w2 + (size_t)t * DD;
    float s = b2[t];
    for (int j = 0; j < DD; j += 4) {
        float4 w4 = *(const float4*)(wr + j);
        s += w4.x * g1[j] + w4.y * g1[j+1] + w4.z * g1[j+2] + w4.w * g1[j+3];
    }
    float rs = wave_reduce_sum(s);
    float rss = wave_reduce_sum(s * s);
    int lane = t & 63, w = t >> 6;
    if (lane == 0) { red[w] = rs; red[8 + w] = rss; }
    __syncthreads();
    float mean = 0.f, msq = 0.f;
    #pragma unroll
    for (int i = 0; i < 8; ++i) { mean += red[i]; msq += red[8 + i]; }
    mean *= (1.0f / DD); msq *= (1.0f / DD);
    float rstd = rsqrtf(msq - mean * mean + 1e-5f);
    e[(size_t)b * DD + t] = (s - mean) * rstd * lng[t] + lnb[t];
}

// ---- templated MFMA GEMM, BK=64, double-buffered LDS (T3-min 2-phase) ----
template<int BM, int BN, int FM, int FN, int WGN, int MODE>
__global__ __launch_bounds__(256) void gemm_t(
    const unsigned short* __restrict__ A, const unsigned short* __restrict__ W,
    const float* __restrict__ bias, const float* __restrict__ resid,
    float* __restrict__ outf, unsigned short* __restrict__ outb,
    int M, int N, int K)
{
    __shared__ __align__(16) unsigned short As[2][BM * 64];
    __shared__ __align__(16) unsigned short Ws[2][BN * 64];
    int bm = blockIdx.y * BM, bn = blockIdx.x * BN;
    int t = threadIdx.x;
    int lane = t & 63, wid = t >> 6;
    int wr = wid / WGN, wc = wid % WGN;
    int l15 = lane & 15, lg = lane >> 4;
    int sr = lane >> 3;
    int sc = ((lane & 7) ^ sr) * 8;
    int ph0 = (lg ^ (l15 & 7)) * 8;
    int ph1 = ((lg + 4) ^ (l15 & 7)) * 8;

    f32x4 acc[FM][FN] = {};
    int nk = K >> 6;

    auto stage = [&](int buf, int ks) {
        int kb = ks * 64;
        #pragma unroll
        for (int i = 0; i < BM / 32; ++i) {
            int row = wid * (BM / 4) + i * 8 + sr;
            gload16(A + (size_t)(bm + row) * K + kb + sc, &As[buf][(wid * (BM / 4) + i * 8) * 64]);
        }
        #pragma unroll
        for (int i = 0; i < BN / 32; ++i) {
            int row = wid * (BN / 4) + i * 8 + sr;
            gload16(W + (size_t)(bn + row) * K + kb + sc, &Ws[buf][(wid * (BN / 4) + i * 8) * 64]);
        }
    };

    stage(0, 0);
    __syncthreads();

    int cur = 0;
    for (int ks = 0; ks < nk; ++ks) {
        if (ks + 1 < nk) stage(cur ^ 1, ks + 1);
        s16x8 af0[FM], af1[FM], wf0[FN], wf1[FN];
        #pragma unroll
        for (int mi = 0; mi < FM; ++mi) {
            int row = wr * FM * 16 + mi * 16 + l15;
            af0[mi] = *(const s16x8*)&As[cur][row * 64 + ph0];
            af1[mi] = *(const s16x8*)&As[cur][row * 64 + ph1];
        }
        #pragma unroll
        for (int ni = 0; ni < FN; ++ni) {
            int row = wc * FN * 16 + ni * 16 + l15;
            wf0[ni] = *(const s16x8*)&Ws[cur][row * 64 + ph0];
            wf1[ni] = *(const s16x8*)&Ws[cur][row * 64 + ph1];
        }
        #pragma unroll
        for (int mi = 0; mi < FM; ++mi)
            #pragma unroll
            for (int ni = 0; ni < FN; ++ni) {
                acc[mi][ni] = __builtin_amdgcn_mfma_f32_16x16x32_bf16(af0[mi], wf0[ni], acc[mi][ni], 0, 0, 0);
                acc[mi][ni] = __builtin_amdgcn_mfma_f32_16x16x32_bf16(af1[mi], wf1[ni], acc[mi][ni], 0, 0, 0);
            }
        __syncthreads();
        cur ^= 1;
    }

    int rbase = (lane >> 4) * 4;
    #pragma unroll
    for (int mi = 0; mi < FM; ++mi) {
        #pragma unroll
        for (int ni = 0; ni < FN; ++ni) {
            int n = bn + wc * FN * 16 + ni * 16 + l15;
            float bzc = (MODE == 4) ? 0.f : bias[n];
            #pragma unroll
            for (int r2 = 0; r2 < 4; ++r2) {
                int m = bm + wr * FM * 16 + mi * 16 + rbase + r2;
                float v = acc[mi][ni][r2] + ((MODE == 4) ? bias[m] : bzc);
                size_t o = (size_t)m * N + n;
                if (MODE == 0)      outf[o] = v;
                else if (MODE == 1) outb[o] = f2bf(v);
                else if (MODE == 2) outf[o] = v + resid[o];
                else if (MODE == 3) outb[o] = f2bf(gelu_exact(v));
                else                outb[o] = f2bf(v);
            }
        }
    }
}

// ------------- MFMA flash attention: natural block order (XCD-balanced), dbuf K/V -------------
// qk: [B*L][1024] bf16 (Q at 0, K at 512). Vt: [512][4096] bf16 = V^T per (h,d) row.
#define SK 72
#define SPB 72
__global__ __launch_bounds__(256) void attn_mfma(
    const unsigned short* __restrict__ qk, const unsigned short* __restrict__ Vt,
    const float* __restrict__ c_local, const float* __restrict__ srow,
    const int* __restrict__ lengths,
    const float* __restrict__ alpha_p,
    unsigned short* __restrict__ o)
{
    __shared__ __align__(16) unsigned short Ks[2][64 * SK];
    __shared__ __align__(16) unsigned short Vts[2][64 * SK];
    __shared__ __align__(16) unsigned short Psb[64 * SPB];

    int id = blockIdx.x;
    int q0 = (id & 15) * 64;
    int hh = (id >> 4) & 7;
    int b  = id >> 7;

    int t  = threadIdx.x;
    int lane = t & 63, w = t >> 6;
    int l15 = lane & 15, lg = lane >> 4;
    int len = lengths[b];
    int nt = (len + 63) >> 6;
    int kt0 = q0 >> 6;
    bool sink_blk = (q0 == 0);
    const float alpha = *alpha_p;

    const unsigned short* qrow = qk + (size_t)(b * LL + q0 + w * 16 + l15) * 1024 + hh * DH;
    s16x8 qf0 = *(const s16x8*)(qrow + lg * 8);
    s16x8 qf1 = *(const s16x8*)(qrow + 32 + lg * 8);
    #pragma unroll
    for (int j = 0; j < 8; ++j) {
        qf0[j] = (short)f2bf(bf2f((unsigned short)qf0[j]) * 0.125f);
        qf1[j] = (short)f2bf(bf2f((unsigned short)qf1[j]) * 0.125f);
    }

    float cm1[4], cp1[4];
    #pragma unroll
    for (int r2 = 0; r2 < 4; ++r2) {
        int qi = q0 + w * 16 + lg * 4 + r2;
        cm1[r2] = 0.f; cp1[r2] = 0.f;
        if (qi >= 1 && qi < len) {
            int src = (qi == 1 || qi == LL - 1) ? qi : qi - 1;
            cm1[r2] = alpha * c_local[(size_t)b * LL + src];
        }
        if (qi + 1 < LL && qi < len)
            cp1[r2] = alpha * c_local[(size_t)b * LL + qi + 1];
    }
    bool need_sink = (sink_blk && w == 0 && lg == 0);

    float m_run[4], l_run[4];
    f32x4 accO[4] = {};
    #pragma unroll
    for (int r2 = 0; r2 < 4; ++r2) { m_run[r2] = -1e30f; l_run[r2] = 0.f; }

    int sr = t >> 3, sc8 = (t & 7) * 8;
    const unsigned short* kbase = qk + (size_t)(b * LL) * 1024 + 512 + hh * DH;
    const unsigned short* vbase = Vt + (size_t)(hh * DH) * MM + b * LL;

    uint4 pk0 = *(const uint4*)(kbase + (size_t)sr * 1024 + sc8);
    uint4 pk1 = *(const uint4*)(kbase + (size_t)(sr + 32) * 1024 + sc8);
    uint4 pv0 = *(const uint4*)(vbase + (size_t)sr * MM + sc8);
    uint4 pv1 = *(const uint4*)(vbase + (size_t)(sr + 32) * MM + sc8);
    *(uint4*)&Ks[0][sr * SK + sc8]         = pk0;
    *(uint4*)&Ks[0][(sr + 32) * SK + sc8]  = pk1;
    *(uint4*)&Vts[0][sr * SK + sc8]        = pv0;
    *(uint4*)&Vts[0][(sr + 32) * SK + sc8] = pv1;
    __syncthreads();

    int cur = 0;
    for (int kt = 0; kt < nt; ++kt) {
        int k0 = kt * 64;
        bool pre = (kt + 1 < nt);
        if (pre) {
            int kn = k0 + 64;
            pk0 = *(const uint4*)(kbase + (size_t)(kn + sr) * 1024 + sc8);
            pk1 = *(const uint4*)(kbase + (size_t)(kn + sr + 32) * 1024 + sc8);
            pv0 = *(const uint4*)(vbase + (size_t)sr * MM + kn + sc8);
            pv1 = *(const uint4*)(vbase + (size_t)(sr + 32) * MM + kn + sc8);
        }

        f32x4 accS[4] = {};
        #pragma unroll
        for (int ct = 0; ct < 4; ++ct) {
            s16x8 kf0 = *(const s16x8*)&Ks[cur][(ct * 16 + l15) * SK + lg * 8];
            s16x8 kf1 = *(const s16x8*)&Ks[cur][(ct * 16 + l15) * SK + 32 + lg * 8];
            accS[ct] = __builtin_amdgcn_mfma_f32_16x16x32_bf16(qf0, kf0, accS[ct], 0, 0, 0);
            accS[ct] = __builtin_amdgcn_mfma_f32_16x16x32_bf16(qf1, kf1, accS[ct], 0, 0, 0);
        }

        float m4[4] = { -1e30f, -1e30f, -1e30f, -1e30f };
        bool slow = sink_blk || (kt >= kt0 - 1 && kt <= kt0 + 1) || (k0 + 64 > len);
        if (!slow) {
            #pragma unroll
            for (int ct = 0; ct < 4; ++ct)
                #pragma unroll
                for (int r2 = 0; r2 < 4; ++r2)
                    m4[r2] = fmaxf(m4[r2], accS[ct][r2]);
        } else if (k0 + 64 <= len) {
            #pragma unroll
            for (int ct = 0; ct < 4; ++ct) {
                int k = k0 + ct * 16 + l15;
                float sink_ct = need_sink ? srow[(size_t)b * LL + k] : 0.f;
                #pragma unroll
                for (int r2 = 0; r2 < 4; ++r2) {
                    int qi = q0 + w * 16 + lg * 4 + r2;
                    float v = accS[ct][r2];
                    if (k == qi - 1) v += cm1[r2];
                    else if (k == qi + 1) v += cp1[r2];
                    if (r2 == 0) v += sink_ct;
                    accS[ct][r2] = v;
                    m4[r2] = fmaxf(m4[r2], v);
                }
            }
        } else {
            #pragma unroll
            for (int ct = 0; ct < 4; ++ct) {
                int k = k0 + ct * 16 + l15;
                bool maskk = (k >= len);
                float sink_ct = need_sink ? srow[(size_t)b * LL + k] : 0.f;
                #pragma unroll
                for (int r2 = 0; r2 < 4; ++r2) {
                    int qi = q0 + w * 16 + lg * 4 + r2;
                    float v = accS[ct][r2];
                    if (k == qi - 1) v += cm1[r2];
                    else if (k == qi + 1 && !maskk) v += cp1[r2];
                    if (r2 == 0) v += sink_ct;
                    if (maskk) v -= 10000.f;
                    accS[ct][r2] = v;
                    m4[r2] = fmaxf(m4[r2], v);
                }
            }
        }

        #pragma unroll
        for (int r2 = 0; r2 < 4; ++r2) {
            #pragma unroll
            for (int msk = 1; msk < 16; msk <<= 1) m4[r2] = fmaxf(m4[r2], __shfl_xor(m4[r2], msk));
            float mnew = fmaxf(m_run[r2], m4[r2]);
            float scl = __expf(m_run[r2] - mnew);
            m_run[r2] = mnew;
            float rowsum = 0.f;
            #pragma unroll
            for (int ct = 0; ct < 4; ++ct) {
                float p = __expf(accS[ct][r2] - mnew);
                rowsum += p;
                Psb[(w * 16 + lg * 4 + r2) * SPB + ct * 16 + l15] = f2bf(p);
            }
            #pragma unroll
            for (int msk = 1; msk < 16; msk <<= 1) rowsum += __shfl_xor(rowsum, msk);
            l_run[r2] = l_run[r2] * scl + rowsum;
            #pragma unroll
            for (int dt = 0; dt < 4; ++dt) accO[dt][r2] *= scl;
        }

        #pragma unroll
        for (int kk = 0; kk < 2; ++kk) {
            s16x8 pf = *(const s16x8*)&Psb[(w * 16 + l15) * SPB + kk * 32 + lg * 8];
            #pragma unroll
            for (int dt = 0; dt < 4; ++dt) {
                s16x8 vf = *(const s16x8*)&Vts[cur][(dt * 16 + l15) * SK + kk * 32 + lg * 8];
                accO[dt] = __builtin_amdgcn_mfma_f32_16x16x32_bf16(pf, vf, accO[dt], 0, 0, 0);
            }
        }

        if (pre) {
            int nxt = cur ^ 1;
            *(uint4*)&Ks[nxt][sr * SK + sc8]         = pk0;
            *(uint4*)&Ks[nxt][(sr + 32) * SK + sc8]  = pk1;
            *(uint4*)&Vts[nxt][sr * SK + sc8]        = pv0;
            *(uint4*)&Vts[nxt][(sr + 32) * SK + sc8] = pv1;
        }
        __syncthreads();
        cur ^= 1;
    }

    #pragma unroll
    for (int r2 = 0; r2 < 4; ++r2) {
        float inv = 1.f / l_run[r2];
        int qi = q0 + w * 16 + lg * 4 + r2;
        #pragma unroll
        for (int dt = 0; dt < 4; ++dt)
            o[(size_t)(b * LL + qi) * DD + hh * DH + dt * 16 + l15] = f2bf(accO[dt][r2] * inv);
    }
}

// ------ embed epilogue: h += e + mask?0:gain*LN(cpe_pre) ------
__global__ __launch_bounds__(256) void embed_ep_kernel(
    const float* __restrict__ cpe_pre, const float* __restrict__ e,
    const int* __restrict__ lengths,
    const float* __restrict__ cpe_g, const float* __restrict__ cpe_lb,
    const float* __restrict__ gain_p, float* __restrict__ h)
{
    int row = blockIdx.x;
    int b = row >> 10, l = row & 1023;
    int t = threadIdx.x;
    __shared__ float red[16];
    const float* cp = cpe_pre + (size_t)row * DD;
    float v0 = cp[t], v1 = cp[t + 256];
    float s = v0 + v1, ss = v0 * v0 + v1 * v1;
    float rs = wave_reduce_sum(s), rss = wave_reduce_sum(ss);
    int lane = t & 63, w = t >> 6;
    if (lane == 0) { red[w] = rs; red[8 + w] = rss; }
    __syncthreads();
    float mean = 0.f, msq = 0.f;
    #pragma unroll
    for (int i = 0; i < 4; ++i) { mean += red[i]; msq += red[8 + i]; }
    mean *= (1.0f / DD); msq *= (1.0f / DD);
    float rstd = rsqrtf(msq - mean * mean + 1e-5f);
    bool maskp = (l >= lengths[b]);
    float gain = *gain_p;
    float pe0 = maskp ? 0.f : gain * ((v0 - mean) * rstd * cpe_g[t] + cpe_lb[t]);
    float pe1 = maskp ? 0.f : gain * ((v1 - mean) * rstd * cpe_g[t + 256] + cpe_lb[t + 256]);
    h[(size_t)row * DD + t]       += e[(size_t)b * DD + t] + pe0;
    h[(size_t)row * DD + t + 256] += e[(size_t)b * DD + t + 256] + pe1;
}

// ---------------- LayerNorm f32 out (final) ----------------
__global__ __launch_bounds__(256) void ln_kernel(
    const float* __restrict__ in, float* __restrict__ out,
    const float* __restrict__ g, const float* __restrict__ bta)
{
    int row = blockIdx.x; int t = threadIdx.x;
    __shared__ float red[16];
    const float* xr = in + (size_t)row * DD;
    float2 v = ((const float2*)xr)[t];
    float s = v.x + v.y, ss = v.x * v.x + v.y * v.y;
    float rs = wave_reduce_sum(s), rss = wave_reduce_sum(ss);
    int lane = t & 63, w = t >> 6;
    if (lane == 0) { red[w] = rs; red[8 + w] = rss; }
    __syncthreads();
    float mean = 0.f, msq = 0.f;
    #pragma unroll
    for (int i = 0; i < 4; ++i) { mean += red[i]; msq += red[8 + i]; }
    mean *= (1.0f / DD); msq *= (1.0f / DD);
    float rstd = rsqrtf(msq - mean * mean + 1e-5f);
    float2 gg = ((const float2*)g)[t], bb = ((const float2*)bta)[t];
    float2 o;
    o.x = (v.x - mean) * rstd * gg.x + bb.x;
    o.y = (v.y - mean) * rstd * gg.y + bb.y;
    ((float2*)(out + (size_t)row * DD))[t] = o;
}

// ---------------- LayerNorm bf16 out ----------------
__global__ __launch_bounds__(256) void ln_bf16_kernel(
    const float* __restrict__ in, unsigned short* __restrict__ out,
    const float* __restrict__ g, const float* __restrict__ bta)
{
    int row = blockIdx.x; int t = threadIdx.x;
    __shared__ float red[16];
    const float* xr = in + (size_t)row * DD;
    float2 v = ((const float2*)xr)[t];
    float s = v.x + v.y, ss = v.x * v.x + v.y * v.y;
    float rs = wave_reduce_sum(s), rss = wave_reduce_sum(ss);
    int lane = t & 63, w = t >> 6;
    if (lane == 0) { red[w] = rs; red[8 + w] = rss; }
    __syncthreads();
    float mean = 0.f, msq = 0.f;
    #pragma unroll
    for (int i = 0; i < 4; ++i) { mean += red[i]; msq += red[8 + i]; }
    mean *= (1.0f / DD); msq *= (1.0f / DD);
    float rstd = rsqrtf(msq - mean * mean + 1e-5f);
    float2 gg = ((const float2*)g)[t], bb = ((const float2*)bta)[t];
    ushort2 o;
    o.x = f2bf((v.x - mean) * rstd * gg.x + bb.x);
    o.y = f2bf((v.y - mean) * rstd * gg.y + bb.y);
    ((ushort2*)(out + (size_t)row * DD))[t] = o;
}

extern "C" void kernel_launch(void* const* d_in, const int* in_sizes, int n_in,
                              void* d_out, int out_size, void* d_ws, size_t ws_size,
                              hipStream_t stream)
{
    const float* x          = (const float*)d_in[0];
    const int*   lengths    = (const int*)  d_in[1];
    const float* input_delay= (const float*)d_in[2];
    const float* c_local    = (const float*)d_in[3];
    const float* c_sink     = (const float*)d_in[4];
    const float* in_w       = (const float*)d_in[5];
    const float* in_b       = (const float*)d_in[6];
    const float* de_w1      = (const float*)d_in[7];
    const float* de_b1      = (const float*)d_in[8];
    const float* de_w2      = (const float*)d_in[9];
    const float* de_b2      = (const float*)d_in[10];
    const float* de_ln_g    = (const float*)d_in[11];
    const float* de_ln_b    = (const float*)d_in[12];
    const float* cpe_w      = (const float*)d_in[13];
    const float* cpe_b      = (const float*)d_in[14];
    const float* cpe_ln_g   = (const float*)d_in[15];
    const float* cpe_ln_b   = (const float*)d_in[16];
    const float* gain       = (const float*)d_in[17];
    const float* alpha      = (const float*)d_in[18];
    const float* beta       = (const float*)d_in[19];
    const float* floorp     = (const float*)d_in[20];
    const float* gammap     = (const float*)d_in[21];
    const float* inproj_w   = (const float*)d_in[22];
    const float* inproj_b   = (const float*)d_in[23];
    const float* outproj_w  = (const float*)d_in[24];
    const float* outproj_b  = (const float*)d_in[25];
    const float* ln1_g      = (const float*)d_in[26];
    const float* ln1_b      = (const float*)d_in[27];
    const float* ln2_g      = (const float*)d_in[28];
    const float* ln2_b      = (const float*)d_in[29];
    const float* ff_w1      = (const float*)d_in[30];
    const float* ff_b1      = (const float*)d_in[31];
    const float* ff_w2      = (const float*)d_in[32];
    const float* ff_b2      = (const float*)d_in[33];
    const float* out_ln_g   = (const float*)d_in[34];
    const float* out_ln_b   = (const float*)d_in[35];

    char* base = (char*)d_ws;
    float* h            = (float*)base;                               // 8 MB
    unsigned short* act1 = (unsigned short*)(base + 8u*1024*1024);    // 4 MB
    char* bigb          = base + 12u*1024*1024;                       // 16 MB shared region
    unsigned short* qkb  = (unsigned short*)bigb;                     // 8 MB (attn phase: Q,K)
    unsigned short* vtb  = (unsigned short*)(bigb + 12u*1024*1024);   // 4 MB (attn phase: V^T [512][4096])
    unsigned short* ffb  = (unsigned short*)bigb;                     // 16 MB (FF phase)
    unsigned short* Zb   = (unsigned short*)bigb;                     // 4.7 MB (embed phase)
    unsigned short* x_bf = (unsigned short*)(bigb + 5u*1024*1024);    // 0.5 MB
    float* cpe_pre       = (float*)(bigb + 8u*1024*1024);             // 8 MB
    unsigned short* w_inproj  = (unsigned short*)(base + 28u*1024*1024);
    unsigned short* w_outproj = w_inproj  + (size_t)3*1536*512;
    unsigned short* w_ff1     = w_outproj + (size_t)3*512*512;
    unsigned short* w_ff2     = w_ff1     + (size_t)3*2048*512;
    unsigned short* w_in      = w_ff2     + (size_t)3*512*2048;
    unsigned short* w_cpe     = w_in      + (size_t)512*64;
    float* e                  = (float*)(w_cpe + (size_t)512*FEATP);
    float* srow               = e + (size_t)BB*DD;

    prep_kernel<<<2048, 256, 0, stream>>>(x, inproj_w, outproj_w, ff_w1, ff_w2, in_w, cpe_w,
                                          x_bf, w_inproj, w_outproj, w_ff1, w_ff2, w_in, w_cpe);
    delay_kernel<<<BB, 512, 0, stream>>>(input_delay, de_w1, de_b1, de_w2, de_b2, de_ln_g, de_ln_b, e);
    build_z_kernel<<<MM, 256, 0, stream>>>(c_local, c_sink, lengths, beta, floorp, gammap, Zb, srow);

    gemm_t<64, 64, 2, 2, 2, 0><<<dim3(DD / 64, MM / 64), 256, 0, stream>>>(
        x_bf, w_in, in_b, nullptr, h, nullptr, MM, DD, DIN);
    gemm_t<64, 64, 2, 2, 2, 0><<<dim3(DD / 64, MM / 64), 256, 0, stream>>>(
        Zb, w_cpe, cpe_b, nullptr, cpe_pre, nullptr, MM, DD, FEATP);
    embed_ep_kernel<<<MM, 256, 0, stream>>>(cpe_pre, e, lengths, cpe_ln_g, cpe_ln_b, gain, h);

    for (int i = 0; i < NLAYER; ++i) {
        const unsigned short* wqk = w_inproj + (size_t)i * 1536 * 512;          // Q,K rows [0,1024)
        const unsigned short* wv  = wqk + (size_t)1024 * 512;                   // V rows [1024,1536)
        ln_bf16_kernel<<<MM, 256, 0, stream>>>(h, act1, ln1_g + (size_t)i * DD, ln1_b + (size_t)i * DD);
        gemm_t<64, 128, 2, 4, 2, 1><<<dim3(1024 / 128, MM / 64), 256, 0, stream>>>(
            act1, wqk, inproj_b + (size_t)i * 1536, nullptr, nullptr, qkb, MM, 1024, DD);
        gemm_t<64, 64, 2, 2, 2, 4><<<dim3(MM / 64, DD / 64), 256, 0, stream>>>(
            wv, act1, inproj_b + (size_t)i * 1536 + 1024, nullptr, nullptr, vtb, DD, MM, DD);
        attn_mfma<<<512, 256, 0, stream>>>(qkb, vtb, c_local, srow, lengths, alpha, act1);
        gemm_t<64, 64, 2, 2, 2, 2><<<dim3(DD / 64, MM / 64), 256, 0, stream>>>(
            act1, w_outproj + (size_t)i * 512 * 512, outproj_b + (size_t)i * DD,
            h, h, nullptr, MM, DD, DD);
        ln_bf16_kernel<<<MM, 256, 0, stream>>>(h, act1, ln2_g + (size_t)i * DD, ln2_b + (size_t)i * DD);
        gemm_t<128, 128, 4, 4, 2, 3><<<dim3(DFF / 128, MM / 128), 256, 0, stream>>>(
            act1, w_ff1 + (size_t)i * 2048 * 512, ff_b1 + (size_t)i * DFF,
            nullptr, nullptr, ffb, MM, DFF, DD);
        gemm_t<64, 64, 2, 2, 2, 2><<<dim3(DD / 64, MM / 64), 256, 0, stream>>>(
            ffb, w_ff2 + (size_t)i * 512 * 2048, ff_b2 + (size_t)i * DD,
            h, h, nullptr, MM, DD, DFF);
    }
    ln_kernel<<<MM, 256, 0, stream>>>(h, (float*)d_out, out_ln_g, out_ln_b);
}

// Round 17
// 429.961 us; speedup vs baseline: 1.3785x; 1.0204x over previous
//
#include <hip/hip_runtime.h>
#include <math.h>

#define BB 4
#define LL 1024
#define DIN 64
#define DD 512
#define HH 8
#define DH 64
#define NLAYER 3
#define DFF 2048
#define FEAT 530
#define FEATP 576
#define MM 4096

typedef float f32x4 __attribute__((ext_vector_type(4)));
typedef short s16x8 __attribute__((ext_vector_type(8)));

__device__ __forceinline__ unsigned short f2bf(float f) {
    unsigned int u = __float_as_uint(f);
    u += 0x7fffu + ((u >> 16) & 1u);
    return (unsigned short)(u >> 16);
}
__device__ __forceinline__ float bf2f(unsigned short u) {
    return __uint_as_float(((unsigned int)u) << 16);
}
__device__ __forceinline__ float gelu_exact(float x) {
    return 0.5f * x * (1.0f + erff(x * 0.7071067811865475f));
}
__device__ __forceinline__ float wave_reduce_sum(float v) {
    #pragma unroll
    for (int o = 32; o; o >>= 1) v += __shfl_down(v, o);
    return v;
}
__device__ __forceinline__ void gload16(const unsigned short* g, unsigned short* l) {
    __builtin_amdgcn_global_load_lds(
        (const __attribute__((address_space(1))) unsigned int*)g,
        (__attribute__((address_space(3))) unsigned int*)l, 16, 0, 0);
}

// ------------- fused prep: all weight f32->bf16 converts + cpe pad -------------
__global__ __launch_bounds__(256) void prep_kernel(
    const float* __restrict__ x, const float* __restrict__ inproj_w,
    const float* __restrict__ outproj_w, const float* __restrict__ ff_w1,
    const float* __restrict__ ff_w2, const float* __restrict__ in_w,
    const float* __restrict__ cpe_w,
    unsigned short* __restrict__ x_bf, unsigned short* __restrict__ w_inproj,
    unsigned short* __restrict__ w_outproj, unsigned short* __restrict__ w_ff1,
    unsigned short* __restrict__ w_ff2, unsigned short* __restrict__ w_in,
    unsigned short* __restrict__ w_cpe)
{
    const int N0 = MM * DIN;
    const int N1 = N0 + 3 * 1536 * 512;
    const int N2 = N1 + 3 * 512 * 512;
    const int N3 = N2 + 3 * 2048 * 512;
    const int N4 = N3 + 3 * 512 * 2048;
    const int N5 = N4 + 512 * 64;
    const int N6 = N5 + 512 * FEATP;
    for (int i = blockIdx.x * 256 + threadIdx.x; i < N6; i += gridDim.x * 256) {
        if (i < N0)      x_bf[i]          = f2bf(x[i]);
        else if (i < N1) w_inproj[i - N0] = f2bf(inproj_w[i - N0]);
        else if (i < N2) w_outproj[i - N1]= f2bf(outproj_w[i - N1]);
        else if (i < N3) w_ff1[i - N2]    = f2bf(ff_w1[i - N2]);
        else if (i < N4) w_ff2[i - N3]    = f2bf(ff_w2[i - N3]);
        else if (i < N5) w_in[i - N4]     = f2bf(in_w[i - N4]);
        else {
            int j = i - N5; int r = j / FEATP, c = j - r * FEATP;
            w_cpe[j] = (c < FEAT) ? f2bf(cpe_w[(size_t)r * FEAT + c]) : 0;
        }
    }
}

// ---------------- build Z[M][576] bf16 + sink row (fused) ----------------
__global__ __launch_bounds__(256) void build_z_kernel(
    const float* __restrict__ c_local, const float* __restrict__ c_sink,
    const int* __restrict__ lengths,
    const float* __restrict__ beta_p, const float* __restrict__ floor_p,
    const float* __restrict__ gamma_p,
    unsigned short* __restrict__ Z, float* __restrict__ srow)
{
    int row = blockIdx.x;
    int b = row >> 10, l = row & 1023;
    int t = threadIdx.x;
    unsigned short* zr = Z + (size_t)row * FEATP;
    for (int d = t; d < DD; d += 256) {
        int i = d >> 1;
        float dv = expf((float)(2 * i) * (-0.017988946135618352f)); // -ln(1e4)/512
        float ang = (float)l * dv;
        zr[d] = f2bf((d & 1) ? cosf(ang) : sinf(ang));
    }
    if (t < 64) {
        float cl = c_local[(size_t)b * LL + l]; cl = fminf(fmaxf(cl, 0.f), 1.f);
        float cs = c_sink [(size_t)b * LL + l]; cs = fminf(fmaxf(cs, 0.f), 1.f);
        float v = 0.f;
        if (t == 0) v = cl;
        else if (t == 1) v = cs;
        else if (t < 10)  { float c = (float)(t - 2) * (1.0f / 7.0f);  float df = (cl - c) / 0.200001f; v = expf(-0.5f * df * df); }
        else if (t < 18)  { float c = (float)(t - 10) * (1.0f / 7.0f); float df = (cs - c) / 0.200001f; v = expf(-0.5f * df * df); }
        zr[512 + t] = (t < 18) ? f2bf(v) : 0;
        if (t == 32) {
            float sv = (*beta_p) * ((*floor_p) + (1.f - (*floor_p)) * powf(cs + 1e-6f, *gamma_p));
            srow[row] = (l < lengths[b]) ? sv : 0.f;
        }
    }
}

// ---------------- delay feature encoder: e[B,D] ----------------
__global__ __launch_bounds__(512) void delay_kernel(
    const float* __restrict__ delay, const float* __restrict__ w1, const float* __restrict__ b1,
    const float* __restrict__ w2, const float* __restrict__ b2,
    const float* __restrict__ lng, const float* __restrict__ lnb,
    float* __restrict__ e)
{
    int b = blockIdx.x;
    int t = threadIdx.x;
    __shared__ float g1[DD];
    __shared__ float red[16];
    float t1 = delay[b] * w1[t] + b1[t];
    g1[t] = gelu_exact(t1);
    __syncthreads();
    const float* wr = w2 + (size_t)t * DD;
    float s = b2[t];
    for (int j = 0; j < DD; j += 4) {
        float4 w4 = *(const float4*)(wr + j);
        s += w4.x * g1[j] + w4.y * g1[j+1] + w4.z * g1[j+2] + w4.w * g1[j+3];
    }
    float rs = wave_reduce_sum(s);
    float rss = wave_reduce_sum(s * s);
    int lane = t & 63, w = t >> 6;
    if (lane == 0) { red[w] = rs; red[8 + w] = rss; }
    __syncthreads();
    float mean = 0.f, msq = 0.f;
    #pragma unroll
    for (int i = 0; i < 8; ++i) { mean += red[i]; msq += red[8 + i]; }
    mean *= (1.0f / DD); msq *= (1.0f / DD);
    float rstd = rsqrtf(msq - mean * mean + 1e-5f);
    e[(size_t)b * DD + t] = (s - mean) * rstd * lng[t] + lnb[t];
}

// ---- GEMM body (BK=64, dbuf LDS, runtime mode), shared by gemm_t and dual kernels ----
template<int BM, int BN, int FM, int FN, int WGN>
__device__ __forceinline__ void gemm_body(
    const unsigned short* __restrict__ A, const unsigned short* __restrict__ W,
    const float* __restrict__ bias, const float* __restrict__ resid,
    float* __restrict__ outf, unsigned short* __restrict__ outb,
    int M, int N, int K, int mode, int bm, int bn,
    unsigned short* As, unsigned short* Ws)   // As: 2*BM*64, Ws: 2*BN*64
{
    int t = threadIdx.x;
    int lane = t & 63, wid = t >> 6;
    int wr = wid / WGN, wc = wid % WGN;
    int l15 = lane & 15, lg = lane >> 4;
    int sr = lane >> 3;
    int sc = ((lane & 7) ^ sr) * 8;
    int ph0 = (lg ^ (l15 & 7)) * 8;
    int ph1 = ((lg + 4) ^ (l15 & 7)) * 8;

    f32x4 acc[FM][FN] = {};
    int nk = K >> 6;

    auto stage = [&](int buf, int ks) {
        int kb = ks * 64;
        #pragma unroll
        for (int i = 0; i < BM / 32; ++i) {
            int row = wid * (BM / 4) + i * 8 + sr;
            gload16(A + (size_t)(bm + row) * K + kb + sc, &As[(size_t)buf * BM * 64 + (wid * (BM / 4) + i * 8) * 64]);
        }
        #pragma unroll
        for (int i = 0; i < BN / 32; ++i) {
            int row = wid * (BN / 4) + i * 8 + sr;
            gload16(W + (size_t)(bn + row) * K + kb + sc, &Ws[(size_t)buf * BN * 64 + (wid * (BN / 4) + i * 8) * 64]);
        }
    };

    stage(0, 0);
    __syncthreads();

    int cur = 0;
    for (int ks = 0; ks < nk; ++ks) {
        if (ks + 1 < nk) stage(cur ^ 1, ks + 1);
        s16x8 af0[FM], af1[FM], wf0[FN], wf1[FN];
        #pragma unroll
        for (int mi = 0; mi < FM; ++mi) {
            int row = wr * FM * 16 + mi * 16 + l15;
            af0[mi] = *(const s16x8*)&As[(size_t)cur * BM * 64 + row * 64 + ph0];
            af1[mi] = *(const s16x8*)&As[(size_t)cur * BM * 64 + row * 64 + ph1];
        }
        #pragma unroll
        for (int ni = 0; ni < FN; ++ni) {
            int row = wc * FN * 16 + ni * 16 + l15;
            wf0[ni] = *(const s16x8*)&Ws[(size_t)cur * BN * 64 + row * 64 + ph0];
            wf1[ni] = *(const s16x8*)&Ws[(size_t)cur * BN * 64 + row * 64 + ph1];
        }
        #pragma unroll
        for (int mi = 0; mi < FM; ++mi)
            #pragma unroll
            for (int ni = 0; ni < FN; ++ni) {
                acc[mi][ni] = __builtin_amdgcn_mfma_f32_16x16x32_bf16(af0[mi], wf0[ni], acc[mi][ni], 0, 0, 0);
                acc[mi][ni] = __builtin_amdgcn_mfma_f32_16x16x32_bf16(af1[mi], wf1[ni], acc[mi][ni], 0, 0, 0);
            }
        __syncthreads();
        cur ^= 1;
    }

    int rbase = (lane >> 4) * 4;
    #pragma unroll
    for (int mi = 0; mi < FM; ++mi) {
        #pragma unroll
        for (int ni = 0; ni < FN; ++ni) {
            int n = bn + wc * FN * 16 + ni * 16 + l15;
            float bzc = (mode == 4) ? 0.f : bias[n];
            #pragma unroll
            for (int r2 = 0; r2 < 4; ++r2) {
                int m = bm + wr * FM * 16 + mi * 16 + rbase + r2;
                float v = acc[mi][ni][r2] + ((mode == 4) ? bias[m] : bzc);
                size_t o = (size_t)m * N + n;
                if (mode == 0)      outf[o] = v;
                else if (mode == 1) outb[o] = f2bf(v);
                else if (mode == 2) outf[o] = v + resid[o];
                else if (mode == 3) outb[o] = f2bf(gelu_exact(v));
                else                outb[o] = f2bf(v);
            }
        }
    }
}

// ---- standalone templated GEMM (same structure as R12/R15) ----
template<int BM, int BN, int FM, int FN, int WGN, int MODE>
__global__ __launch_bounds__(256) void gemm_t(
    const unsigned short* __restrict__ A, const unsigned short* __restrict__ W,
    const float* __restrict__ bias, const float* __restrict__ resid,
    float* __restrict__ outf, unsigned short* __restrict__ outb,
    int M, int N, int K)
{
    __shared__ __align__(16) unsigned short As[2 * BM * 64];
    __shared__ __align__(16) unsigned short Ws[2 * BN * 64];
    gemm_body<BM, BN, FM, FN, WGN>(A, W, bias, resid, outf, outb, M, N, K, MODE,
                                   blockIdx.y * BM, blockIdx.x * BN, As, Ws);
}

// ---- dual dispatch: h0 GEMM (512 blocks) + cpe GEMM (512 blocks) ----
__global__ __launch_bounds__(256) void gemm_pre_dual(
    const unsigned short* __restrict__ x_bf, const unsigned short* __restrict__ w_in,
    const float* __restrict__ in_b, float* __restrict__ h,
    const unsigned short* __restrict__ Zb, const unsigned short* __restrict__ w_cpe,
    const float* __restrict__ cpe_b, float* __restrict__ cpe_pre)
{
    __shared__ __align__(16) unsigned short As[2 * 64 * 64];
    __shared__ __align__(16) unsigned short Ws[2 * 64 * 64];
    int id = blockIdx.x;
    if (id < 512) {
        gemm_body<64, 64, 2, 2, 2>(x_bf, w_in, in_b, nullptr, h, nullptr,
                                   MM, DD, DIN, 0, (id >> 3) * 64, (id & 7) * 64, As, Ws);
    } else {
        id -= 512;
        gemm_body<64, 64, 2, 2, 2>(Zb, w_cpe, cpe_b, nullptr, cpe_pre, nullptr,
                                   MM, DD, FEATP, 0, (id >> 3) * 64, (id & 7) * 64, As, Ws);
    }
}

// ---- dual dispatch: QK GEMM (1024 blocks) + V^T GEMM (512 blocks) ----
__global__ __launch_bounds__(256) void gemm_qkv_dual(
    const unsigned short* __restrict__ act1,
    const unsigned short* __restrict__ wqk, const float* __restrict__ qk_bias,
    unsigned short* __restrict__ qkb,
    const unsigned short* __restrict__ wv, const float* __restrict__ v_bias,
    unsigned short* __restrict__ vtb)
{
    __shared__ __align__(16) unsigned short As[2 * 64 * 64];
    __shared__ __align__(16) unsigned short Ws[2 * 64 * 64];
    int id = blockIdx.x;
    if (id < 1024) {
        // QK: out[4096][1024] bf16 (mode 1); tiles 64 rows x 16 cols
        gemm_body<64, 64, 2, 2, 2>(act1, wqk, qk_bias, nullptr, nullptr, qkb,
                                   MM, 1024, DD, 1, (id >> 4) * 64, (id & 15) * 64, As, Ws);
    } else {
        id -= 1024;
        // V^T: out[512][4096] bf16, row bias (mode 4); tiles 8 rows x 64 cols
        gemm_body<64, 64, 2, 2, 2>(wv, act1, v_bias, nullptr, nullptr, vtb,
                                   DD, MM, DD, 4, (id >> 6) * 64, (id & 63) * 64, As, Ws);
    }
}

// ------------- MFMA flash attention: natural block order (XCD-balanced), dbuf K/V -------------
// qk: [B*L][1024] bf16 (Q at 0, K at 512). Vt: [512][4096] bf16 = V^T per (h,d) row.
#define SK 72
#define SPB 72
__global__ __launch_bounds__(256) void attn_mfma(
    const unsigned short* __restrict__ qk, const unsigned short* __restrict__ Vt,
    const float* __restrict__ c_local, const float* __restrict__ srow,
    const int* __restrict__ lengths,
    const float* __restrict__ alpha_p,
    unsigned short* __restrict__ o)
{
    __shared__ __align__(16) unsigned short Ks[2][64 * SK];
    __shared__ __align__(16) unsigned short Vts[2][64 * SK];
    __shared__ __align__(16) unsigned short Psb[64 * SPB];

    int id = blockIdx.x;
    int q0 = (id & 15) * 64;
    int hh = (id >> 4) & 7;
    int b  = id >> 7;

    int t  = threadIdx.x;
    int lane = t & 63, w = t >> 6;
    int l15 = lane & 15, lg = lane >> 4;
    int len = lengths[b];
    int nt = (len + 63) >> 6;
    int kt0 = q0 >> 6;
    bool sink_blk = (q0 == 0);
    const float alpha = *alpha_p;

    const unsigned short* qrow = qk + (size_t)(b * LL + q0 + w * 16 + l15) * 1024 + hh * DH;
    s16x8 qf0 = *(const s16x8*)(qrow + lg * 8);
    s16x8 qf1 = *(const s16x8*)(qrow + 32 + lg * 8);
    #pragma unroll
    for (int j = 0; j < 8; ++j) {
        qf0[j] = (short)f2bf(bf2f((unsigned short)qf0[j]) * 0.125f);
        qf1[j] = (short)f2bf(bf2f((unsigned short)qf1[j]) * 0.125f);
    }

    float cm1[4], cp1[4];
    #pragma unroll
    for (int r2 = 0; r2 < 4; ++r2) {
        int qi = q0 + w * 16 + lg * 4 + r2;
        cm1[r2] = 0.f; cp1[r2] = 0.f;
        if (qi >= 1 && qi < len) {
            int src = (qi == 1 || qi == LL - 1) ? qi : qi - 1;
            cm1[r2] = alpha * c_local[(size_t)b * LL + src];
        }
        if (qi + 1 < LL && qi < len)
            cp1[r2] = alpha * c_local[(size_t)b * LL + qi + 1];
    }
    bool need_sink = (sink_blk && w == 0 && lg == 0);

    float m_run[4], l_run[4];
    f32x4 accO[4] = {};
    #pragma unroll
    for (int r2 = 0; r2 < 4; ++r2) { m_run[r2] = -1e30f; l_run[r2] = 0.f; }

    int sr = t >> 3, sc8 = (t & 7) * 8;
    const unsigned short* kbase = qk + (size_t)(b * LL) * 1024 + 512 + hh * DH;
    const unsigned short* vbase = Vt + (size_t)(hh * DH) * MM + b * LL;

    uint4 pk0 = *(const uint4*)(kbase + (size_t)sr * 1024 + sc8);
    uint4 pk1 = *(const uint4*)(kbase + (size_t)(sr + 32) * 1024 + sc8);
    uint4 pv0 = *(const uint4*)(vbase + (size_t)sr * MM + sc8);
    uint4 pv1 = *(const uint4*)(vbase + (size_t)(sr + 32) * MM + sc8);
    *(uint4*)&Ks[0][sr * SK + sc8]         = pk0;
    *(uint4*)&Ks[0][(sr + 32) * SK + sc8]  = pk1;
    *(uint4*)&Vts[0][sr * SK + sc8]        = pv0;
    *(uint4*)&Vts[0][(sr + 32) * SK + sc8] = pv1;
    __syncthreads();

    int cur = 0;
    for (int kt = 0; kt < nt; ++kt) {
        int k0 = kt * 64;
        bool pre = (kt + 1 < nt);
        if (pre) {
            int kn = k0 + 64;
            pk0 = *(const uint4*)(kbase + (size_t)(kn + sr) * 1024 + sc8);
            pk1 = *(const uint4*)(kbase + (size_t)(kn + sr + 32) * 1024 + sc8);
            pv0 = *(const uint4*)(vbase + (size_t)sr * MM + kn + sc8);
            pv1 = *(const uint4*)(vbase + (size_t)(sr + 32) * MM + kn + sc8);
        }

        f32x4 accS[4] = {};
        #pragma unroll
        for (int ct = 0; ct < 4; ++ct) {
            s16x8 kf0 = *(const s16x8*)&Ks[cur][(ct * 16 + l15) * SK + lg * 8];
            s16x8 kf1 = *(const s16x8*)&Ks[cur][(ct * 16 + l15) * SK + 32 + lg * 8];
            accS[ct] = __builtin_amdgcn_mfma_f32_16x16x32_bf16(qf0, kf0, accS[ct], 0, 0, 0);
            accS[ct] = __builtin_amdgcn_mfma_f32_16x16x32_bf16(qf1, kf1, accS[ct], 0, 0, 0);
        }

        float m4[4] = { -1e30f, -1e30f, -1e30f, -1e30f };
        bool slow = sink_blk || (kt >= kt0 - 1 && kt <= kt0 + 1) || (k0 + 64 > len);
        if (!slow) {
            #pragma unroll
            for (int ct = 0; ct < 4; ++ct)
                #pragma unroll
                for (int r2 = 0; r2 < 4; ++r2)
                    m4[r2] = fmaxf(m4[r2], accS[ct][r2]);
        } else if (k0 + 64 <= len) {
            #pragma unroll
            for (int ct = 0; ct < 4; ++ct) {
                int k = k0 + ct * 16 + l15;
                float sink_ct = need_sink ? srow[(size_t)b * LL + k] : 0.f;
                #pragma unroll
                for (int r2 = 0; r2 < 4; ++r2) {
                    int qi = q0 + w * 16 + lg * 4 + r2;
                    float v = accS[ct][r2];
                    if (k == qi - 1) v += cm1[r2];
                    else if (k == qi + 1) v += cp1[r2];
                    if (r2 == 0) v += sink_ct;
                    accS[ct][r2] = v;
                    m4[r2] = fmaxf(m4[r2], v);
                }
            }
        } else {
            #pragma unroll
            for (int ct = 0; ct < 4; ++ct) {
                int k = k0 + ct * 16 + l15;
                bool maskk = (k >= len);
                float sink_ct = need_sink ? srow[(size_t)b * LL + k] : 0.f;
                #pragma unroll
                for (int r2 = 0; r2 < 4; ++r2) {
                    int qi = q0 + w * 16 + lg * 4 + r2;
                    float v = accS[ct][r2];
                    if (k == qi - 1) v += cm1[r2];
                    else if (k == qi + 1 && !maskk) v += cp1[r2];
                    if (r2 == 0) v += sink_ct;
                    if (maskk) v -= 10000.f;
                    accS[ct][r2] = v;
                    m4[r2] = fmaxf(m4[r2], v);
                }
            }
        }

        #pragma unroll
        for (int r2 = 0; r2 < 4; ++r2) {
            #pragma unroll
            for (int msk = 1; msk < 16; msk <<= 1) m4[r2] = fmaxf(m4[r2], __shfl_xor(m4[r2], msk));
            float mnew = fmaxf(m_run[r2], m4[r2]);
            float scl = __expf(m_run[r2] - mnew);
            m_run[r2] = mnew;
            float rowsum = 0.f;
            #pragma unroll
            for (int ct = 0; ct < 4; ++ct) {
                float p = __expf(accS[ct][r2] - mnew);
                rowsum += p;
                Psb[(w * 16 + lg * 4 + r2) * SPB + ct * 16 + l15] = f2bf(p);
            }
            #pragma unroll
            for (int msk = 1; msk < 16; msk <<= 1) rowsum += __shfl_xor(rowsum, msk);
            l_run[r2] = l_run[r2] * scl + rowsum;
            #pragma unroll
            for (int dt = 0; dt < 4; ++dt) accO[dt][r2] *= scl;
        }

        #pragma unroll
        for (int kk = 0; kk < 2; ++kk) {
            s16x8 pf = *(const s16x8*)&Psb[(w * 16 + l15) * SPB + kk * 32 + lg * 8];
            #pragma unroll
            for (int dt = 0; dt < 4; ++dt) {
                s16x8 vf = *(const s16x8*)&Vts[cur][(dt * 16 + l15) * SK + kk * 32 + lg * 8];
                accO[dt] = __builtin_amdgcn_mfma_f32_16x16x32_bf16(pf, vf, accO[dt], 0, 0, 0);
            }
        }

        if (pre) {
            int nxt = cur ^ 1;
            *(uint4*)&Ks[nxt][sr * SK + sc8]         = pk0;
            *(uint4*)&Ks[nxt][(sr + 32) * SK + sc8]  = pk1;
            *(uint4*)&Vts[nxt][sr * SK + sc8]        = pv0;
            *(uint4*)&Vts[nxt][(sr + 32) * SK + sc8] = pv1;
        }
        __syncthreads();
        cur ^= 1;
    }

    #pragma unroll
    for (int r2 = 0; r2 < 4; ++r2) {
        float inv = 1.f / l_run[r2];
        int qi = q0 + w * 16 + lg * 4 + r2;
        #pragma unroll
        for (int dt = 0; dt < 4; ++dt)
            o[(size_t)(b * LL + qi) * DD + hh * DH + dt * 16 + l15] = f2bf(accO[dt][r2] * inv);
    }
}

// ------ embed epilogue: h += e + mask?0:gain*LN(cpe_pre) ------
__global__ __launch_bounds__(256) void embed_ep_kernel(
    const float* __restrict__ cpe_pre, const float* __restrict__ e,
    const int* __restrict__ lengths,
    const float* __restrict__ cpe_g, const float* __restrict__ cpe_lb,
    const float* __restrict__ gain_p, float* __restrict__ h)
{
    int row = blockIdx.x;
    int b = row >> 10, l = row & 1023;
    int t = threadIdx.x;
    __shared__ float red[16];
    const float* cp = cpe_pre + (size_t)row * DD;
    float v0 = cp[t], v1 = cp[t + 256];
    float s = v0 + v1, ss = v0 * v0 + v1 * v1;
    float rs = wave_reduce_sum(s), rss = wave_reduce_sum(ss);
    int lane = t & 63, w = t >> 6;
    if (lane == 0) { red[w] = rs; red[8 + w] = rss; }
    __syncthreads();
    float mean = 0.f, msq = 0.f;
    #pragma unroll
    for (int i = 0; i < 4; ++i) { mean += red[i]; msq += red[8 + i]; }
    mean *= (1.0f / DD); msq *= (1.0f / DD);
    float rstd = rsqrtf(msq - mean * mean + 1e-5f);
    bool maskp = (l >= lengths[b]);
    float gain = *gain_p;
    float pe0 = maskp ? 0.f : gain * ((v0 - mean) * rstd * cpe_g[t] + cpe_lb[t]);
    float pe1 = maskp ? 0.f : gain * ((v1 - mean) * rstd * cpe_g[t + 256] + cpe_lb[t + 256]);
    h[(size_t)row * DD + t]       += e[(size_t)b * DD + t] + pe0;
    h[(size_t)row * DD + t + 256] += e[(size_t)b * DD + t + 256] + pe1;
}

// ---------------- LayerNorm f32 out (final) ----------------
__global__ __launch_bounds__(256) void ln_kernel(
    const float* __restrict__ in, float* __restrict__ out,
    const float* __restrict__ g, const float* __restrict__ bta)
{
    int row = blockIdx.x; int t = threadIdx.x;
    __shared__ float red[16];
    const float* xr = in + (size_t)row * DD;
    float2 v = ((const float2*)xr)[t];
    float s = v.x + v.y, ss = v.x * v.x + v.y * v.y;
    float rs = wave_reduce_sum(s), rss = wave_reduce_sum(ss);
    int lane = t & 63, w = t >> 6;
    if (lane == 0) { red[w] = rs; red[8 + w] = rss; }
    __syncthreads();
    float mean = 0.f, msq = 0.f;
    #pragma unroll
    for (int i = 0; i < 4; ++i) { mean += red[i]; msq += red[8 + i]; }
    mean *= (1.0f / DD); msq *= (1.0f / DD);
    float rstd = rsqrtf(msq - mean * mean + 1e-5f);
    float2 gg = ((const float2*)g)[t], bb = ((const float2*)bta)[t];
    float2 o;
    o.x = (v.x - mean) * rstd * gg.x + bb.x;
    o.y = (v.y - mean) * rstd * gg.y + bb.y;
    ((float2*)(out + (size_t)row * DD))[t] = o;
}

// ---------------- LayerNorm bf16 out ----------------
__global__ __launch_bounds__(256) void ln_bf16_kernel(
    const float* __restrict__ in, unsigned short* __restrict__ out,
    const float* __restrict__ g, const float* __restrict__ bta)
{
    int row = blockIdx.x; int t = threadIdx.x;
    __shared__ float red[16];
    const float* xr = in + (size_t)row * DD;
    float2 v = ((const float2*)xr)[t];
    float s = v.x + v.y, ss = v.x * v.x + v.y * v.y;
    float rs = wave_reduce_sum(s), rss = wave_reduce_sum(ss);
    int lane = t & 63, w = t >> 6;
    if (lane == 0) { red[w] = rs; red[8 + w] = rss; }
    __syncthreads();
    float mean = 0.f, msq = 0.f;
    #pragma unroll
    for (int i = 0; i < 4; ++i) { mean += red[i]; msq += red[8 + i]; }
    mean *= (1.0f / DD); msq *= (1.0f / DD);
    float rstd = rsqrtf(msq - mean * mean + 1e-5f);
    float2 gg = ((const float2*)g)[t], bb = ((const float2*)bta)[t];
    ushort2 o;
    o.x = f2bf((v.x - mean) * rstd * gg.x + bb.x);
    o.y = f2bf((v.y - mean) * rstd * gg.y + bb.y);
    ((ushort2*)(out + (size_t)row * DD))[t] = o;
}

extern "C" void kernel_launch(void* const* d_in, const int* in_sizes, int n_in,
                              void* d_out, int out_size, void* d_ws, size_t ws_size,
                              hipStream_t stream)
{
    const float* x          = (const float*)d_in[0];
    const int*   lengths    = (const int*)  d_in[1];
    const float* input_delay= (const float*)d_in[2];
    const float* c_local    = (const float*)d_in[3];
    const float* c_sink     = (const float*)d_in[4];
    const float* in_w       = (const float*)d_in[5];
    const float* in_b       = (const float*)d_in[6];
    const float* de_w1      = (const float*)d_in[7];
    const float* de_b1      = (const float*)d_in[8];
    const float* de_w2      = (const float*)d_in[9];
    const float* de_b2      = (const float*)d_in[10];
    const float* de_ln_g    = (const float*)d_in[11];
    const float* de_ln_b    = (const float*)d_in[12];
    const float* cpe_w      = (const float*)d_in[13];
    const float* cpe_b      = (const float*)d_in[14];
    const float* cpe_ln_g   = (const float*)d_in[15];
    const float* cpe_ln_b   = (const float*)d_in[16];
    const float* gain       = (const float*)d_in[17];
    const float* alpha      = (const float*)d_in[18];
    const float* beta       = (const float*)d_in[19];
    const float* floorp     = (const float*)d_in[20];
    const float* gammap     = (const float*)d_in[21];
    const float* inproj_w   = (const float*)d_in[22];
    const float* inproj_b   = (const float*)d_in[23];
    const float* outproj_w  = (const float*)d_in[24];
    const float* outproj_b  = (const float*)d_in[25];
    const float* ln1_g      = (const float*)d_in[26];
    const float* ln1_b      = (const float*)d_in[27];
    const float* ln2_g      = (const float*)d_in[28];
    const float* ln2_b      = (const float*)d_in[29];
    const float* ff_w1      = (const float*)d_in[30];
    const float* ff_b1      = (const float*)d_in[31];
    const float* ff_w2      = (const float*)d_in[32];
    const float* ff_b2      = (const float*)d_in[33];
    const float* out_ln_g   = (const float*)d_in[34];
    const float* out_ln_b   = (const float*)d_in[35];

    char* base = (char*)d_ws;
    float* h            = (float*)base;                               // 8 MB
    unsigned short* act1 = (unsigned short*)(base + 8u*1024*1024);    // 4 MB
    char* bigb          = base + 12u*1024*1024;                       // 16 MB shared region
    unsigned short* qkb  = (unsigned short*)bigb;                     // 8 MB (attn phase: Q,K)
    unsigned short* vtb  = (unsigned short*)(bigb + 12u*1024*1024);   // 4 MB (attn phase: V^T [512][4096])
    unsigned short* ffb  = (unsigned short*)bigb;                     // 16 MB (FF phase)
    unsigned short* Zb   = (unsigned short*)bigb;                     // 4.7 MB (embed phase)
    unsigned short* x_bf = (unsigned short*)(bigb + 5u*1024*1024);    // 0.5 MB
    float* cpe_pre       = (float*)(bigb + 8u*1024*1024);             // 8 MB
    unsigned short* w_inproj  = (unsigned short*)(base + 28u*1024*1024);
    unsigned short* w_outproj = w_inproj  + (size_t)3*1536*512;
    unsigned short* w_ff1     = w_outproj + (size_t)3*512*512;
    unsigned short* w_ff2     = w_ff1     + (size_t)3*2048*512;
    unsigned short* w_in      = w_ff2     + (size_t)3*512*2048;
    unsigned short* w_cpe     = w_in      + (size_t)512*64;
    float* e                  = (float*)(w_cpe + (size_t)512*FEATP);
    float* srow               = e + (size_t)BB*DD;

    prep_kernel<<<2048, 256, 0, stream>>>(x, inproj_w, outproj_w, ff_w1, ff_w2, in_w, cpe_w,
                                          x_bf, w_inproj, w_outproj, w_ff1, w_ff2, w_in, w_cpe);
    delay_kernel<<<BB, 512, 0, stream>>>(input_delay, de_w1, de_b1, de_w2, de_b2, de_ln_g, de_ln_b, e);
    build_z_kernel<<<MM, 256, 0, stream>>>(c_local, c_sink, lengths, beta, floorp, gammap, Zb, srow);

    // h0 GEMM + cpe GEMM fused into one dispatch (independent)
    gemm_pre_dual<<<1024, 256, 0, stream>>>(x_bf, w_in, in_b, h, Zb, w_cpe, cpe_b, cpe_pre);
    embed_ep_kernel<<<MM, 256, 0, stream>>>(cpe_pre, e, lengths, cpe_ln_g, cpe_ln_b, gain, h);

    for (int i = 0; i < NLAYER; ++i) {
        const unsigned short* wqk = w_inproj + (size_t)i * 1536 * 512;          // Q,K rows [0,1024)
        const unsigned short* wv  = wqk + (size_t)1024 * 512;                   // V rows [1024,1536)
        ln_bf16_kernel<<<MM, 256, 0, stream>>>(h, act1, ln1_g + (size_t)i * DD, ln1_b + (size_t)i * DD);
        // QK GEMM + V^T GEMM fused into one dispatch (both read act1 only)
        gemm_qkv_dual<<<1536, 256, 0, stream>>>(act1, wqk, inproj_b + (size_t)i * 1536,
                                                qkb, wv, inproj_b + (size_t)i * 1536 + 1024, vtb);
        attn_mfma<<<512, 256, 0, stream>>>(qkb, vtb, c_local, srow, lengths, alpha, act1);
        gemm_t<64, 64, 2, 2, 2, 2><<<dim3(DD / 64, MM / 64), 256, 0, stream>>>(
            act1, w_outproj + (size_t)i * 512 * 512, outproj_b + (size_t)i * DD,
            h, h, nullptr, MM, DD, DD);
        ln_bf16_kernel<<<MM, 256, 0, stream>>>(h, act1, ln2_g + (size_t)i * DD, ln2_b + (size_t)i * DD);
        gemm_t<128, 128, 4, 4, 2, 3><<<dim3(DFF / 128, MM / 128), 256, 0, stream>>>(
            act1, w_ff1 + (size_t)i * 2048 * 512, ff_b1 + (size_t)i * DFF,
            nullptr, nullptr, ffb, MM, DFF, DD);
        gemm_t<64, 64, 2, 2, 2, 2><<<dim3(DD / 64, MM / 64), 256, 0, stream>>>(
            ffb, w_ff2 + (size_t)i * 512 * 2048, ff_b2 + (size_t)i * DD,
            h, h, nullptr, MM, DD, DFF);
    }
    ln_kernel<<<MM, 256, 0, stream>>>(h, (float*)d_out, out_ln_g, out_ln_b);
}

// Round 18
// 429.501 us; speedup vs baseline: 1.3800x; 1.0011x over previous
//
#include <hip/hip_runtime.h>
#include <math.h>

#define BB 4
#define LL 1024
#define DIN 64
#define DD 512
#define HH 8
#define DH 64
#define NLAYER 3
#define DFF 2048
#define FEAT 530
#define FEATP 576
#define MM 4096

typedef float f32x4 __attribute__((ext_vector_type(4)));
typedef short s16x8 __attribute__((ext_vector_type(8)));

__device__ __forceinline__ unsigned short f2bf(float f) {
    unsigned int u = __float_as_uint(f);
    u += 0x7fffu + ((u >> 16) & 1u);
    return (unsigned short)(u >> 16);
}
__device__ __forceinline__ float bf2f(unsigned short u) {
    return __uint_as_float(((unsigned int)u) << 16);
}
__device__ __forceinline__ float gelu_exact(float x) {
    return 0.5f * x * (1.0f + erff(x * 0.7071067811865475f));
}
__device__ __forceinline__ float wave_reduce_sum(float v) {
    #pragma unroll
    for (int o = 32; o; o >>= 1) v += __shfl_down(v, o);
    return v;
}
__device__ __forceinline__ void gload16(const unsigned short* g, unsigned short* l) {
    __builtin_amdgcn_global_load_lds(
        (const __attribute__((address_space(1))) unsigned int*)g,
        (__attribute__((address_space(3))) unsigned int*)l, 16, 0, 0);
}

// ------------- fused prologue: build_z+sink (4096) | prep converts (2048) | delay (4) -------------
__global__ __launch_bounds__(256) void prologue_kernel(
    // build_z inputs
    const float* __restrict__ c_local, const float* __restrict__ c_sink,
    const int* __restrict__ lengths,
    const float* __restrict__ beta_p, const float* __restrict__ floor_p,
    const float* __restrict__ gamma_p,
    unsigned short* __restrict__ Z, float* __restrict__ srow,
    // prep inputs
    const float* __restrict__ x, const float* __restrict__ inproj_w,
    const float* __restrict__ outproj_w, const float* __restrict__ ff_w1,
    const float* __restrict__ ff_w2, const float* __restrict__ in_w,
    const float* __restrict__ cpe_w,
    unsigned short* __restrict__ x_bf, unsigned short* __restrict__ w_inproj,
    unsigned short* __restrict__ w_outproj, unsigned short* __restrict__ w_ff1,
    unsigned short* __restrict__ w_ff2, unsigned short* __restrict__ w_in,
    unsigned short* __restrict__ w_cpe,
    // delay inputs
    const float* __restrict__ delay, const float* __restrict__ de_w1, const float* __restrict__ de_b1,
    const float* __restrict__ de_w2, const float* __restrict__ de_b2,
    const float* __restrict__ de_lng, const float* __restrict__ de_lnb,
    float* __restrict__ e)
{
    int blk = blockIdx.x;
    int t = threadIdx.x;

    if (blk < MM) {
        // ---- build Z row + sink ----
        int row = blk;
        int b = row >> 10, l = row & 1023;
        unsigned short* zr = Z + (size_t)row * FEATP;
        for (int d = t; d < DD; d += 256) {
            int i = d >> 1;
            float dv = expf((float)(2 * i) * (-0.017988946135618352f)); // -ln(1e4)/512
            float ang = (float)l * dv;
            zr[d] = f2bf((d & 1) ? cosf(ang) : sinf(ang));
        }
        if (t < 64) {
            float cl = c_local[(size_t)b * LL + l]; cl = fminf(fmaxf(cl, 0.f), 1.f);
            float cs = c_sink [(size_t)b * LL + l]; cs = fminf(fmaxf(cs, 0.f), 1.f);
            float v = 0.f;
            if (t == 0) v = cl;
            else if (t == 1) v = cs;
            else if (t < 10)  { float c = (float)(t - 2) * (1.0f / 7.0f);  float df = (cl - c) / 0.200001f; v = expf(-0.5f * df * df); }
            else if (t < 18)  { float c = (float)(t - 10) * (1.0f / 7.0f); float df = (cs - c) / 0.200001f; v = expf(-0.5f * df * df); }
            zr[512 + t] = (t < 18) ? f2bf(v) : 0;
            if (t == 32) {
                float sv = (*beta_p) * ((*floor_p) + (1.f - (*floor_p)) * powf(cs + 1e-6f, *gamma_p));
                srow[row] = (l < lengths[b]) ? sv : 0.f;
            }
        }
    } else if (blk < MM + 2048) {
        // ---- prep converts (grid-stride over 2048 virtual blocks) ----
        const int N0 = MM * DIN;
        const int N1 = N0 + 3 * 1536 * 512;
        const int N2 = N1 + 3 * 512 * 512;
        const int N3 = N2 + 3 * 2048 * 512;
        const int N4 = N3 + 3 * 512 * 2048;
        const int N5 = N4 + 512 * 64;
        const int N6 = N5 + 512 * FEATP;
        for (int i = (blk - MM) * 256 + t; i < N6; i += 2048 * 256) {
            if (i < N0)      x_bf[i]          = f2bf(x[i]);
            else if (i < N1) w_inproj[i - N0] = f2bf(inproj_w[i - N0]);
            else if (i < N2) w_outproj[i - N1]= f2bf(outproj_w[i - N1]);
            else if (i < N3) w_ff1[i - N2]    = f2bf(ff_w1[i - N2]);
            else if (i < N4) w_ff2[i - N3]    = f2bf(ff_w2[i - N3]);
            else if (i < N5) w_in[i - N4]     = f2bf(in_w[i - N4]);
            else {
                int j = i - N5; int r = j / FEATP, c = j - r * FEATP;
                w_cpe[j] = (c < FEAT) ? f2bf(cpe_w[(size_t)r * FEAT + c]) : 0;
            }
        }
    } else {
        // ---- delay encoder, 256 threads (each owns rows t and t+256) ----
        __shared__ float g1[DD];
        __shared__ float red[16];
        int b = blk - (MM + 2048);
        float d0 = delay[b];
        g1[t]       = gelu_exact(d0 * de_w1[t]       + de_b1[t]);
        g1[t + 256] = gelu_exact(d0 * de_w1[t + 256] + de_b1[t + 256]);
        __syncthreads();
        float s0 = de_b2[t], s1 = de_b2[t + 256];
        const float* wr0 = de_w2 + (size_t)t * DD;
        const float* wr1 = de_w2 + (size_t)(t + 256) * DD;
        for (int j = 0; j < DD; j += 4) {
            float4 a4 = *(const float4*)(wr0 + j);
            float4 b4 = *(const float4*)(wr1 + j);
            float gj0 = g1[j], gj1 = g1[j+1], gj2 = g1[j+2], gj3 = g1[j+3];
            s0 += a4.x * gj0 + a4.y * gj1 + a4.z * gj2 + a4.w * gj3;
            s1 += b4.x * gj0 + b4.y * gj1 + b4.z * gj2 + b4.w * gj3;
        }
        float s = s0 + s1, ss = s0 * s0 + s1 * s1;
        float rs = wave_reduce_sum(s), rss = wave_reduce_sum(ss);
        int lane = t & 63, w = t >> 6;
        if (lane == 0) { red[w] = rs; red[8 + w] = rss; }
        __syncthreads();
        float mean = 0.f, msq = 0.f;
        #pragma unroll
        for (int i = 0; i < 4; ++i) { mean += red[i]; msq += red[8 + i]; }
        mean *= (1.0f / DD); msq *= (1.0f / DD);
        float rstd = rsqrtf(msq - mean * mean + 1e-5f);
        e[(size_t)b * DD + t]       = (s0 - mean) * rstd * de_lng[t]       + de_lnb[t];
        e[(size_t)b * DD + t + 256] = (s1 - mean) * rstd * de_lng[t + 256] + de_lnb[t + 256];
    }
}

// ---- GEMM body (BK=64, dbuf LDS, runtime mode), shared by gemm_t and dual kernels ----
template<int BM, int BN, int FM, int FN, int WGN>
__device__ __forceinline__ void gemm_body(
    const unsigned short* __restrict__ A, const unsigned short* __restrict__ W,
    const float* __restrict__ bias, const float* __restrict__ resid,
    float* __restrict__ outf, unsigned short* __restrict__ outb,
    int M, int N, int K, int mode, int bm, int bn,
    unsigned short* As, unsigned short* Ws)   // As: 2*BM*64, Ws: 2*BN*64
{
    int t = threadIdx.x;
    int lane = t & 63, wid = t >> 6;
    int wr = wid / WGN, wc = wid % WGN;
    int l15 = lane & 15, lg = lane >> 4;
    int sr = lane >> 3;
    int sc = ((lane & 7) ^ sr) * 8;
    int ph0 = (lg ^ (l15 & 7)) * 8;
    int ph1 = ((lg + 4) ^ (l15 & 7)) * 8;

    f32x4 acc[FM][FN] = {};
    int nk = K >> 6;

    auto stage = [&](int buf, int ks) {
        int kb = ks * 64;
        #pragma unroll
        for (int i = 0; i < BM / 32; ++i) {
            int row = wid * (BM / 4) + i * 8 + sr;
            gload16(A + (size_t)(bm + row) * K + kb + sc, &As[(size_t)buf * BM * 64 + (wid * (BM / 4) + i * 8) * 64]);
        }
        #pragma unroll
        for (int i = 0; i < BN / 32; ++i) {
            int row = wid * (BN / 4) + i * 8 + sr;
            gload16(W + (size_t)(bn + row) * K + kb + sc, &Ws[(size_t)buf * BN * 64 + (wid * (BN / 4) + i * 8) * 64]);
        }
    };

    stage(0, 0);
    __syncthreads();

    int cur = 0;
    for (int ks = 0; ks < nk; ++ks) {
        if (ks + 1 < nk) stage(cur ^ 1, ks + 1);
        s16x8 af0[FM], af1[FM], wf0[FN], wf1[FN];
        #pragma unroll
        for (int mi = 0; mi < FM; ++mi) {
            int row = wr * FM * 16 + mi * 16 + l15;
            af0[mi] = *(const s16x8*)&As[(size_t)cur * BM * 64 + row * 64 + ph0];
            af1[mi] = *(const s16x8*)&As[(size_t)cur * BM * 64 + row * 64 + ph1];
        }
        #pragma unroll
        for (int ni = 0; ni < FN; ++ni) {
            int row = wc * FN * 16 + ni * 16 + l15;
            wf0[ni] = *(const s16x8*)&Ws[(size_t)cur * BN * 64 + row * 64 + ph0];
            wf1[ni] = *(const s16x8*)&Ws[(size_t)cur * BN * 64 + row * 64 + ph1];
        }
        #pragma unroll
        for (int mi = 0; mi < FM; ++mi)
            #pragma unroll
            for (int ni = 0; ni < FN; ++ni) {
                acc[mi][ni] = __builtin_amdgcn_mfma_f32_16x16x32_bf16(af0[mi], wf0[ni], acc[mi][ni], 0, 0, 0);
                acc[mi][ni] = __builtin_amdgcn_mfma_f32_16x16x32_bf16(af1[mi], wf1[ni], acc[mi][ni], 0, 0, 0);
            }
        __syncthreads();
        cur ^= 1;
    }

    int rbase = (lane >> 4) * 4;
    #pragma unroll
    for (int mi = 0; mi < FM; ++mi) {
        #pragma unroll
        for (int ni = 0; ni < FN; ++ni) {
            int n = bn + wc * FN * 16 + ni * 16 + l15;
            float bzc = (mode == 4) ? 0.f : bias[n];
            #pragma unroll
            for (int r2 = 0; r2 < 4; ++r2) {
                int m = bm + wr * FM * 16 + mi * 16 + rbase + r2;
                float v = acc[mi][ni][r2] + ((mode == 4) ? bias[m] : bzc);
                size_t o = (size_t)m * N + n;
                if (mode == 0)      outf[o] = v;
                else if (mode == 1) outb[o] = f2bf(v);
                else if (mode == 2) outf[o] = v + resid[o];
                else if (mode == 3) outb[o] = f2bf(gelu_exact(v));
                else                outb[o] = f2bf(v);
            }
        }
    }
}

// ---- standalone templated GEMM ----
template<int BM, int BN, int FM, int FN, int WGN, int MODE>
__global__ __launch_bounds__(256) void gemm_t(
    const unsigned short* __restrict__ A, const unsigned short* __restrict__ W,
    const float* __restrict__ bias, const float* __restrict__ resid,
    float* __restrict__ outf, unsigned short* __restrict__ outb,
    int M, int N, int K)
{
    __shared__ __align__(16) unsigned short As[2 * BM * 64];
    __shared__ __align__(16) unsigned short Ws[2 * BN * 64];
    gemm_body<BM, BN, FM, FN, WGN>(A, W, bias, resid, outf, outb, M, N, K, MODE,
                                   blockIdx.y * BM, blockIdx.x * BN, As, Ws);
}

// ---- dual dispatch: h0 GEMM (512 blocks) + cpe GEMM (512 blocks) ----
__global__ __launch_bounds__(256) void gemm_pre_dual(
    const unsigned short* __restrict__ x_bf, const unsigned short* __restrict__ w_in,
    const float* __restrict__ in_b, float* __restrict__ h,
    const unsigned short* __restrict__ Zb, const unsigned short* __restrict__ w_cpe,
    const float* __restrict__ cpe_b, float* __restrict__ cpe_pre)
{
    __shared__ __align__(16) unsigned short As[2 * 64 * 64];
    __shared__ __align__(16) unsigned short Ws[2 * 64 * 64];
    int id = blockIdx.x;
    if (id < 512) {
        gemm_body<64, 64, 2, 2, 2>(x_bf, w_in, in_b, nullptr, h, nullptr,
                                   MM, DD, DIN, 0, (id >> 3) * 64, (id & 7) * 64, As, Ws);
    } else {
        id -= 512;
        gemm_body<64, 64, 2, 2, 2>(Zb, w_cpe, cpe_b, nullptr, cpe_pre, nullptr,
                                   MM, DD, FEATP, 0, (id >> 3) * 64, (id & 7) * 64, As, Ws);
    }
}

// ---- dual dispatch: QK GEMM (1024 blocks) + V^T GEMM (512 blocks) ----
__global__ __launch_bounds__(256) void gemm_qkv_dual(
    const unsigned short* __restrict__ act1,
    const unsigned short* __restrict__ wqk, const float* __restrict__ qk_bias,
    unsigned short* __restrict__ qkb,
    const unsigned short* __restrict__ wv, const float* __restrict__ v_bias,
    unsigned short* __restrict__ vtb)
{
    __shared__ __align__(16) unsigned short As[2 * 64 * 64];
    __shared__ __align__(16) unsigned short Ws[2 * 64 * 64];
    int id = blockIdx.x;
    if (id < 1024) {
        gemm_body<64, 64, 2, 2, 2>(act1, wqk, qk_bias, nullptr, nullptr, qkb,
                                   MM, 1024, DD, 1, (id >> 4) * 64, (id & 15) * 64, As, Ws);
    } else {
        id -= 1024;
        gemm_body<64, 64, 2, 2, 2>(wv, act1, v_bias, nullptr, nullptr, vtb,
                                   DD, MM, DD, 4, (id >> 6) * 64, (id & 63) * 64, As, Ws);
    }
}

// ------------- MFMA flash attention: natural block order (XCD-balanced), dbuf K/V -------------
#define SK 72
#define SPB 72
__global__ __launch_bounds__(256) void attn_mfma(
    const unsigned short* __restrict__ qk, const unsigned short* __restrict__ Vt,
    const float* __restrict__ c_local, const float* __restrict__ srow,
    const int* __restrict__ lengths,
    const float* __restrict__ alpha_p,
    unsigned short* __restrict__ o)
{
    __shared__ __align__(16) unsigned short Ks[2][64 * SK];
    __shared__ __align__(16) unsigned short Vts[2][64 * SK];
    __shared__ __align__(16) unsigned short Psb[64 * SPB];

    int id = blockIdx.x;
    int q0 = (id & 15) * 64;
    int hh = (id >> 4) & 7;
    int b  = id >> 7;

    int t  = threadIdx.x;
    int lane = t & 63, w = t >> 6;
    int l15 = lane & 15, lg = lane >> 4;
    int len = lengths[b];
    int nt = (len + 63) >> 6;
    int kt0 = q0 >> 6;
    bool sink_blk = (q0 == 0);
    const float alpha = *alpha_p;

    const unsigned short* qrow = qk + (size_t)(b * LL + q0 + w * 16 + l15) * 1024 + hh * DH;
    s16x8 qf0 = *(const s16x8*)(qrow + lg * 8);
    s16x8 qf1 = *(const s16x8*)(qrow + 32 + lg * 8);
    #pragma unroll
    for (int j = 0; j < 8; ++j) {
        qf0[j] = (short)f2bf(bf2f((unsigned short)qf0[j]) * 0.125f);
        qf1[j] = (short)f2bf(bf2f((unsigned short)qf1[j]) * 0.125f);
    }

    float cm1[4], cp1[4];
    #pragma unroll
    for (int r2 = 0; r2 < 4; ++r2) {
        int qi = q0 + w * 16 + lg * 4 + r2;
        cm1[r2] = 0.f; cp1[r2] = 0.f;
        if (qi >= 1 && qi < len) {
            int src = (qi == 1 || qi == LL - 1) ? qi : qi - 1;
            cm1[r2] = alpha * c_local[(size_t)b * LL + src];
        }
        if (qi + 1 < LL && qi < len)
            cp1[r2] = alpha * c_local[(size_t)b * LL + qi + 1];
    }
    bool need_sink = (sink_blk && w == 0 && lg == 0);

    float m_run[4], l_run[4];
    f32x4 accO[4] = {};
    #pragma unroll
    for (int r2 = 0; r2 < 4; ++r2) { m_run[r2] = -1e30f; l_run[r2] = 0.f; }

    int sr = t >> 3, sc8 = (t & 7) * 8;
    const unsigned short* kbase = qk + (size_t)(b * LL) * 1024 + 512 + hh * DH;
    const unsigned short* vbase = Vt + (size_t)(hh * DH) * MM + b * LL;

    uint4 pk0 = *(const uint4*)(kbase + (size_t)sr * 1024 + sc8);
    uint4 pk1 = *(const uint4*)(kbase + (size_t)(sr + 32) * 1024 + sc8);
    uint4 pv0 = *(const uint4*)(vbase + (size_t)sr * MM + sc8);
    uint4 pv1 = *(const uint4*)(vbase + (size_t)(sr + 32) * MM + sc8);
    *(uint4*)&Ks[0][sr * SK + sc8]         = pk0;
    *(uint4*)&Ks[0][(sr + 32) * SK + sc8]  = pk1;
    *(uint4*)&Vts[0][sr * SK + sc8]        = pv0;
    *(uint4*)&Vts[0][(sr + 32) * SK + sc8] = pv1;
    __syncthreads();

    int cur = 0;
    for (int kt = 0; kt < nt; ++kt) {
        int k0 = kt * 64;
        bool pre = (kt + 1 < nt);
        if (pre) {
            int kn = k0 + 64;
            pk0 = *(const uint4*)(kbase + (size_t)(kn + sr) * 1024 + sc8);
            pk1 = *(const uint4*)(kbase + (size_t)(kn + sr + 32) * 1024 + sc8);
            pv0 = *(const uint4*)(vbase + (size_t)sr * MM + kn + sc8);
            pv1 = *(const uint4*)(vbase + (size_t)(sr + 32) * MM + kn + sc8);
        }

        f32x4 accS[4] = {};
        #pragma unroll
        for (int ct = 0; ct < 4; ++ct) {
            s16x8 kf0 = *(const s16x8*)&Ks[cur][(ct * 16 + l15) * SK + lg * 8];
            s16x8 kf1 = *(const s16x8*)&Ks[cur][(ct * 16 + l15) * SK + 32 + lg * 8];
            accS[ct] = __builtin_amdgcn_mfma_f32_16x16x32_bf16(qf0, kf0, accS[ct], 0, 0, 0);
            accS[ct] = __builtin_amdgcn_mfma_f32_16x16x32_bf16(qf1, kf1, accS[ct], 0, 0, 0);
        }

        float m4[4] = { -1e30f, -1e30f, -1e30f, -1e30f };
        bool slow = sink_blk || (kt >= kt0 - 1 && kt <= kt0 + 1) || (k0 + 64 > len);
        if (!slow) {
            #pragma unroll
            for (int ct = 0; ct < 4; ++ct)
                #pragma unroll
                for (int r2 = 0; r2 < 4; ++r2)
                    m4[r2] = fmaxf(m4[r2], accS[ct][r2]);
        } else if (k0 + 64 <= len) {
            #pragma unroll
            for (int ct = 0; ct < 4; ++ct) {
                int k = k0 + ct * 16 + l15;
                float sink_ct = need_sink ? srow[(size_t)b * LL + k] : 0.f;
                #pragma unroll
                for (int r2 = 0; r2 < 4; ++r2) {
                    int qi = q0 + w * 16 + lg * 4 + r2;
                    float v = accS[ct][r2];
                    if (k == qi - 1) v += cm1[r2];
                    else if (k == qi + 1) v += cp1[r2];
                    if (r2 == 0) v += sink_ct;
                    accS[ct][r2] = v;
                    m4[r2] = fmaxf(m4[r2], v);
                }
            }
        } else {
            #pragma unroll
            for (int ct = 0; ct < 4; ++ct) {
                int k = k0 + ct * 16 + l15;
                bool maskk = (k >= len);
                float sink_ct = need_sink ? srow[(size_t)b * LL + k] : 0.f;
                #pragma unroll
                for (int r2 = 0; r2 < 4; ++r2) {
                    int qi = q0 + w * 16 + lg * 4 + r2;
                    float v = accS[ct][r2];
                    if (k == qi - 1) v += cm1[r2];
                    else if (k == qi + 1 && !maskk) v += cp1[r2];
                    if (r2 == 0) v += sink_ct;
                    if (maskk) v -= 10000.f;
                    accS[ct][r2] = v;
                    m4[r2] = fmaxf(m4[r2], v);
                }
            }
        }

        #pragma unroll
        for (int r2 = 0; r2 < 4; ++r2) {
            #pragma unroll
            for (int msk = 1; msk < 16; msk <<= 1) m4[r2] = fmaxf(m4[r2], __shfl_xor(m4[r2], msk));
            float mnew = fmaxf(m_run[r2], m4[r2]);
            float scl = __expf(m_run[r2] - mnew);
            m_run[r2] = mnew;
            float rowsum = 0.f;
            #pragma unroll
            for (int ct = 0; ct < 4; ++ct) {
                float p = __expf(accS[ct][r2] - mnew);
                rowsum += p;
                Psb[(w * 16 + lg * 4 + r2) * SPB + ct * 16 + l15] = f2bf(p);
            }
            #pragma unroll
            for (int msk = 1; msk < 16; msk <<= 1) rowsum += __shfl_xor(rowsum, msk);
            l_run[r2] = l_run[r2] * scl + rowsum;
            #pragma unroll
            for (int dt = 0; dt < 4; ++dt) accO[dt][r2] *= scl;
        }

        #pragma unroll
        for (int kk = 0; kk < 2; ++kk) {
            s16x8 pf = *(const s16x8*)&Psb[(w * 16 + l15) * SPB + kk * 32 + lg * 8];
            #pragma unroll
            for (int dt = 0; dt < 4; ++dt) {
                s16x8 vf = *(const s16x8*)&Vts[cur][(dt * 16 + l15) * SK + kk * 32 + lg * 8];
                accO[dt] = __builtin_amdgcn_mfma_f32_16x16x32_bf16(pf, vf, accO[dt], 0, 0, 0);
            }
        }

        if (pre) {
            int nxt = cur ^ 1;
            *(uint4*)&Ks[nxt][sr * SK + sc8]         = pk0;
            *(uint4*)&Ks[nxt][(sr + 32) * SK + sc8]  = pk1;
            *(uint4*)&Vts[nxt][sr * SK + sc8]        = pv0;
            *(uint4*)&Vts[nxt][(sr + 32) * SK + sc8] = pv1;
        }
        __syncthreads();
        cur ^= 1;
    }

    #pragma unroll
    for (int r2 = 0; r2 < 4; ++r2) {
        float inv = 1.f / l_run[r2];
        int qi = q0 + w * 16 + lg * 4 + r2;
        #pragma unroll
        for (int dt = 0; dt < 4; ++dt)
            o[(size_t)(b * LL + qi) * DD + hh * DH + dt * 16 + l15] = f2bf(accO[dt][r2] * inv);
    }
}

// ------ embed epilogue: h += e + mask?0:gain*LN(cpe_pre) ------
__global__ __launch_bounds__(256) void embed_ep_kernel(
    const float* __restrict__ cpe_pre, const float* __restrict__ e,
    const int* __restrict__ lengths,
    const float* __restrict__ cpe_g, const float* __restrict__ cpe_lb,
    const float* __restrict__ gain_p, float* __restrict__ h)
{
    int row = blockIdx.x;
    int b = row >> 10, l = row & 1023;
    int t = threadIdx.x;
    __shared__ float red[16];
    const float* cp = cpe_pre + (size_t)row * DD;
    float v0 = cp[t], v1 = cp[t + 256];
    float s = v0 + v1, ss = v0 * v0 + v1 * v1;
    float rs = wave_reduce_sum(s), rss = wave_reduce_sum(ss);
    int lane = t & 63, w = t >> 6;
    if (lane == 0) { red[w] = rs; red[8 + w] = rss; }
    __syncthreads();
    float mean = 0.f, msq = 0.f;
    #pragma unroll
    for (int i = 0; i < 4; ++i) { mean += red[i]; msq += red[8 + i]; }
    mean *= (1.0f / DD); msq *= (1.0f / DD);
    float rstd = rsqrtf(msq - mean * mean + 1e-5f);
    bool maskp = (l >= lengths[b]);
    float gain = *gain_p;
    float pe0 = maskp ? 0.f : gain * ((v0 - mean) * rstd * cpe_g[t] + cpe_lb[t]);
    float pe1 = maskp ? 0.f : gain * ((v1 - mean) * rstd * cpe_g[t + 256] + cpe_lb[t + 256]);
    h[(size_t)row * DD + t]       += e[(size_t)b * DD + t] + pe0;
    h[(size_t)row * DD + t + 256] += e[(size_t)b * DD + t + 256] + pe1;
}

// ---------------- LayerNorm f32 out (final) ----------------
__global__ __launch_bounds__(256) void ln_kernel(
    const float* __restrict__ in, float* __restrict__ out,
    const float* __restrict__ g, const float* __restrict__ bta)
{
    int row = blockIdx.x; int t = threadIdx.x;
    __shared__ float red[16];
    const float* xr = in + (size_t)row * DD;
    float2 v = ((const float2*)xr)[t];
    float s = v.x + v.y, ss = v.x * v.x + v.y * v.y;
    float rs = wave_reduce_sum(s), rss = wave_reduce_sum(ss);
    int lane = t & 63, w = t >> 6;
    if (lane == 0) { red[w] = rs; red[8 + w] = rss; }
    __syncthreads();
    float mean = 0.f, msq = 0.f;
    #pragma unroll
    for (int i = 0; i < 4; ++i) { mean += red[i]; msq += red[8 + i]; }
    mean *= (1.0f / DD); msq *= (1.0f / DD);
    float rstd = rsqrtf(msq - mean * mean + 1e-5f);
    float2 gg = ((const float2*)g)[t], bb = ((const float2*)bta)[t];
    float2 o;
    o.x = (v.x - mean) * rstd * gg.x + bb.x;
    o.y = (v.y - mean) * rstd * gg.y + bb.y;
    ((float2*)(out + (size_t)row * DD))[t] = o;
}

// ---------------- LayerNorm bf16 out ----------------
__global__ __launch_bounds__(256) void ln_bf16_kernel(
    const float* __restrict__ in, unsigned short* __restrict__ out,
    const float* __restrict__ g, const float* __restrict__ bta)
{
    int row = blockIdx.x; int t = threadIdx.x;
    __shared__ float red[16];
    const float* xr = in + (size_t)row * DD;
    float2 v = ((const float2*)xr)[t];
    float s = v.x + v.y, ss = v.x * v.x + v.y * v.y;
    float rs = wave_reduce_sum(s), rss = wave_reduce_sum(ss);
    int lane = t & 63, w = t >> 6;
    if (lane == 0) { red[w] = rs; red[8 + w] = rss; }
    __syncthreads();
    float mean = 0.f, msq = 0.f;
    #pragma unroll
    for (int i = 0; i < 4; ++i) { mean += red[i]; msq += red[8 + i]; }
    mean *= (1.0f / DD); msq *= (1.0f / DD);
    float rstd = rsqrtf(msq - mean * mean + 1e-5f);
    float2 gg = ((const float2*)g)[t], bb = ((const float2*)bta)[t];
    ushort2 o;
    o.x = f2bf((v.x - mean) * rstd * gg.x + bb.x);
    o.y = f2bf((v.y - mean) * rstd * gg.y + bb.y);
    ((ushort2*)(out + (size_t)row * DD))[t] = o;
}

extern "C" void kernel_launch(void* const* d_in, const int* in_sizes, int n_in,
                              void* d_out, int out_size, void* d_ws, size_t ws_size,
                              hipStream_t stream)
{
    const float* x          = (const float*)d_in[0];
    const int*   lengths    = (const int*)  d_in[1];
    const float* input_delay= (const float*)d_in[2];
    const float* c_local    = (const float*)d_in[3];
    const float* c_sink     = (const float*)d_in[4];
    const float* in_w       = (const float*)d_in[5];
    const float* in_b       = (const float*)d_in[6];
    const float* de_w1      = (const float*)d_in[7];
    const float* de_b1      = (const float*)d_in[8];
    const float* de_w2      = (const float*)d_in[9];
    const float* de_b2      = (const float*)d_in[10];
    const float* de_ln_g    = (const float*)d_in[11];
    const float* de_ln_b    = (const float*)d_in[12];
    const float* cpe_w      = (const float*)d_in[13];
    const float* cpe_b      = (const float*)d_in[14];
    const float* cpe_ln_g   = (const float*)d_in[15];
    const float* cpe_ln_b   = (const float*)d_in[16];
    const float* gain       = (const float*)d_in[17];
    const float* alpha      = (const float*)d_in[18];
    const float* beta       = (const float*)d_in[19];
    const float* floorp     = (const float*)d_in[20];
    const float* gammap     = (const float*)d_in[21];
    const float* inproj_w   = (const float*)d_in[22];
    const float* inproj_b   = (const float*)d_in[23];
    const float* outproj_w  = (const float*)d_in[24];
    const float* outproj_b  = (const float*)d_in[25];
    const float* ln1_g      = (const float*)d_in[26];
    const float* ln1_b      = (const float*)d_in[27];
    const float* ln2_g      = (const float*)d_in[28];
    const float* ln2_b      = (const float*)d_in[29];
    const float* ff_w1      = (const float*)d_in[30];
    const float* ff_b1      = (const float*)d_in[31];
    const float* ff_w2      = (const float*)d_in[32];
    const float* ff_b2      = (const float*)d_in[33];
    const float* out_ln_g   = (const float*)d_in[34];
    const float* out_ln_b   = (const float*)d_in[35];

    char* base = (char*)d_ws;
    float* h            = (float*)base;                               // 8 MB
    unsigned short* act1 = (unsigned short*)(base + 8u*1024*1024);    // 4 MB
    char* bigb          = base + 12u*1024*1024;                       // 16 MB shared region
    unsigned short* qkb  = (unsigned short*)bigb;                     // 8 MB (attn phase: Q,K)
    unsigned short* vtb  = (unsigned short*)(bigb + 12u*1024*1024);   // 4 MB (attn phase: V^T [512][4096])
    unsigned short* ffb  = (unsigned short*)bigb;                     // 16 MB (FF phase)
    unsigned short* Zb   = (unsigned short*)bigb;                     // 4.7 MB (embed phase)
    unsigned short* x_bf = (unsigned short*)(bigb + 5u*1024*1024);    // 0.5 MB
    float* cpe_pre       = (float*)(bigb + 8u*1024*1024);             // 8 MB
    unsigned short* w_inproj  = (unsigned short*)(base + 28u*1024*1024);
    unsigned short* w_outproj = w_inproj  + (size_t)3*1536*512;
    unsigned short* w_ff1     = w_outproj + (size_t)3*512*512;
    unsigned short* w_ff2     = w_ff1     + (size_t)3*2048*512;
    unsigned short* w_in      = w_ff2     + (size_t)3*512*2048;
    unsigned short* w_cpe     = w_in      + (size_t)512*64;
    float* e                  = (float*)(w_cpe + (size_t)512*FEATP);
    float* srow               = e + (size_t)BB*DD;

    // fused prologue: build_z (4096) | prep (2048) | delay (4)
    prologue_kernel<<<MM + 2048 + BB, 256, 0, stream>>>(
        c_local, c_sink, lengths, beta, floorp, gammap, Zb, srow,
        x, inproj_w, outproj_w, ff_w1, ff_w2, in_w, cpe_w,
        x_bf, w_inproj, w_outproj, w_ff1, w_ff2, w_in, w_cpe,
        input_delay, de_w1, de_b1, de_w2, de_b2, de_ln_g, de_ln_b, e);

    // h0 GEMM + cpe GEMM fused into one dispatch (independent)
    gemm_pre_dual<<<1024, 256, 0, stream>>>(x_bf, w_in, in_b, h, Zb, w_cpe, cpe_b, cpe_pre);
    embed_ep_kernel<<<MM, 256, 0, stream>>>(cpe_pre, e, lengths, cpe_ln_g, cpe_ln_b, gain, h);

    for (int i = 0; i < NLAYER; ++i) {
        const unsigned short* wqk = w_inproj + (size_t)i * 1536 * 512;          // Q,K rows [0,1024)
        const unsigned short* wv  = wqk + (size_t)1024 * 512;                   // V rows [1024,1536)
        ln_bf16_kernel<<<MM, 256, 0, stream>>>(h, act1, ln1_g + (size_t)i * DD, ln1_b + (size_t)i * DD);
        gemm_qkv_dual<<<1536, 256, 0, stream>>>(act1, wqk, inproj_b + (size_t)i * 1536,
                                                qkb, wv, inproj_b + (size_t)i * 1536 + 1024, vtb);
        attn_mfma<<<512, 256, 0, stream>>>(qkb, vtb, c_local, srow, lengths, alpha, act1);
        gemm_t<64, 64, 2, 2, 2, 2><<<dim3(DD / 64, MM / 64), 256, 0, stream>>>(
            act1, w_outproj + (size_t)i * 512 * 512, outproj_b + (size_t)i * DD,
            h, h, nullptr, MM, DD, DD);
        ln_bf16_kernel<<<MM, 256, 0, stream>>>(h, act1, ln2_g + (size_t)i * DD, ln2_b + (size_t)i * DD);
        gemm_t<128, 128, 4, 4, 2, 3><<<dim3(DFF / 128, MM / 128), 256, 0, stream>>>(
            act1, w_ff1 + (size_t)i * 2048 * 512, ff_b1 + (size_t)i * DFF,
            nullptr, nullptr, ffb, MM, DFF, DD);
        gemm_t<64, 64, 2, 2, 2, 2><<<dim3(DD / 64, MM / 64), 256, 0, stream>>>(
            ffb, w_ff2 + (size_t)i * 512 * 2048, ff_b2 + (size_t)i * DD,
            h, h, nullptr, MM, DD, DFF);
    }
    ln_kernel<<<MM, 256, 0, stream>>>(h, (float*)d_out, out_ln_g, out_ln_b);
}

// Round 19
// 423.968 us; speedup vs baseline: 1.3980x; 1.0130x over previous
//
#include <hip/hip_runtime.h>
#include <math.h>

#define BB 4
#define LL 1024
#define DIN 64
#define DD 512
#define HH 8
#define DH 64
#define NLAYER 3
#define DFF 2048
#define FEAT 530
#define FEATP 576
#define MM 4096

typedef float f32x4 __attribute__((ext_vector_type(4)));
typedef short s16x8 __attribute__((ext_vector_type(8)));

__device__ __forceinline__ unsigned short f2bf(float f) {
    unsigned int u = __float_as_uint(f);
    u += 0x7fffu + ((u >> 16) & 1u);
    return (unsigned short)(u >> 16);
}
__device__ __forceinline__ float bf2f(unsigned short u) {
    return __uint_as_float(((unsigned int)u) << 16);
}
__device__ __forceinline__ float gelu_exact(float x) {
    return 0.5f * x * (1.0f + erff(x * 0.7071067811865475f));
}
__device__ __forceinline__ float wave_reduce_sum(float v) {
    #pragma unroll
    for (int o = 32; o; o >>= 1) v += __shfl_down(v, o);
    return v;
}
__device__ __forceinline__ void gload16(const unsigned short* g, unsigned short* l) {
    __builtin_amdgcn_global_load_lds(
        (const __attribute__((address_space(1))) unsigned int*)g,
        (__attribute__((address_space(3))) unsigned int*)l, 16, 0, 0);
}

// ------------- fused prologue: PE/z (1024) | vectorized prep (2048) | delay (4) -------------
__global__ __launch_bounds__(256) void prologue_kernel(
    const float* __restrict__ c_local, const float* __restrict__ c_sink,
    const int* __restrict__ lengths,
    const float* __restrict__ beta_p, const float* __restrict__ floor_p,
    const float* __restrict__ gamma_p,
    unsigned short* __restrict__ Z, float* __restrict__ srow,
    const float* __restrict__ x, const float* __restrict__ inproj_w,
    const float* __restrict__ outproj_w, const float* __restrict__ ff_w1,
    const float* __restrict__ ff_w2, const float* __restrict__ in_w,
    const float* __restrict__ cpe_w,
    unsigned short* __restrict__ x_bf, unsigned short* __restrict__ w_inproj,
    unsigned short* __restrict__ w_outproj, unsigned short* __restrict__ w_ff1,
    unsigned short* __restrict__ w_ff2, unsigned short* __restrict__ w_in,
    unsigned short* __restrict__ w_cpe,
    const float* __restrict__ delay, const float* __restrict__ de_w1, const float* __restrict__ de_b1,
    const float* __restrict__ de_w2, const float* __restrict__ de_b2,
    const float* __restrict__ de_lng, const float* __restrict__ de_lnb,
    float* __restrict__ e)
{
    int blk = blockIdx.x;
    int t = threadIdx.x;

    if (blk < LL) {
        // ---- PE row l (shared by all 4 batches) + per-(b,l) tails ----
        int l = blk;
        for (int d = t; d < DD; d += 256) {
            int i = d >> 1;
            float dv = expf((float)(2 * i) * (-0.017988946135618352f)); // -ln(1e4)/512
            float ang = (float)l * dv;
            unsigned short pv = f2bf((d & 1) ? cosf(ang) : sinf(ang));
            #pragma unroll
            for (int bb = 0; bb < 4; ++bb)
                Z[(size_t)(bb * LL + l) * FEATP + d] = pv;
        }
        // tails: 4 groups of 64 threads, group bb covers pad slots j=0..63
        {
            int bb = t >> 6, j = t & 63;
            float cl = c_local[(size_t)bb * LL + l]; cl = fminf(fmaxf(cl, 0.f), 1.f);
            float cs = c_sink [(size_t)bb * LL + l]; cs = fminf(fmaxf(cs, 0.f), 1.f);
            float v = 0.f;
            if (j == 0) v = cl;
            else if (j == 1) v = cs;
            else if (j < 10)  { float c = (float)(j - 2) * (1.0f / 7.0f);  float df = (cl - c) / 0.200001f; v = expf(-0.5f * df * df); }
            else if (j < 18)  { float c = (float)(j - 10) * (1.0f / 7.0f); float df = (cs - c) / 0.200001f; v = expf(-0.5f * df * df); }
            Z[(size_t)(bb * LL + l) * FEATP + 512 + j] = (j < 18) ? f2bf(v) : 0;
            if (j == 32) {
                float sv = (*beta_p) * ((*floor_p) + (1.f - (*floor_p)) * powf(cs + 1e-6f, *gamma_p));
                srow[bb * LL + l] = (l < lengths[bb]) ? sv : 0.f;
            }
        }
    } else if (blk < LL + 2048) {
        // ---- vectorized prep converts (float4 -> ushort4) ----
        const int N0 = MM * DIN;
        const int N1 = N0 + 3 * 1536 * 512;
        const int N2 = N1 + 3 * 512 * 512;
        const int N3 = N2 + 3 * 2048 * 512;
        const int N4 = N3 + 3 * 512 * 2048;
        const int N5 = N4 + 512 * 64;                 // all boundaries are multiples of 4
        int vb = blk - LL;
        for (int v = vb * 256 + t; v < N5 / 4; v += 2048 * 256) {
            int i = v * 4;
            const float* src; unsigned short* dst;
            if (i < N0)      { src = x + i;              dst = x_bf + i; }
            else if (i < N1) { src = inproj_w + (i - N0);  dst = w_inproj + (i - N0); }
            else if (i < N2) { src = outproj_w + (i - N1); dst = w_outproj + (i - N1); }
            else if (i < N3) { src = ff_w1 + (i - N2);     dst = w_ff1 + (i - N2); }
            else if (i < N4) { src = ff_w2 + (i - N3);     dst = w_ff2 + (i - N3); }
            else             { src = in_w + (i - N4);      dst = w_in + (i - N4); }
            float4 f = *(const float4*)src;
            ushort4 o4;
            o4.x = f2bf(f.x); o4.y = f2bf(f.y); o4.z = f2bf(f.z); o4.w = f2bf(f.w);
            *(ushort4*)dst = o4;
        }
        // cpe pad region (misaligned source rows): scalar
        for (int j = vb * 256 + t; j < 512 * FEATP; j += 2048 * 256) {
            int r = j / FEATP, c = j - r * FEATP;
            w_cpe[j] = (c < FEAT) ? f2bf(cpe_w[(size_t)r * FEAT + c]) : 0;
        }
    } else {
        // ---- delay encoder, 256 threads (each owns rows t and t+256) ----
        __shared__ float g1[DD];
        __shared__ float red[16];
        int b = blk - (LL + 2048);
        float d0 = delay[b];
        g1[t]       = gelu_exact(d0 * de_w1[t]       + de_b1[t]);
        g1[t + 256] = gelu_exact(d0 * de_w1[t + 256] + de_b1[t + 256]);
        __syncthreads();
        float s0 = de_b2[t], s1 = de_b2[t + 256];
        const float* wr0 = de_w2 + (size_t)t * DD;
        const float* wr1 = de_w2 + (size_t)(t + 256) * DD;
        for (int j = 0; j < DD; j += 4) {
            float4 a4 = *(const float4*)(wr0 + j);
            float4 b4 = *(const float4*)(wr1 + j);
            float gj0 = g1[j], gj1 = g1[j+1], gj2 = g1[j+2], gj3 = g1[j+3];
            s0 += a4.x * gj0 + a4.y * gj1 + a4.z * gj2 + a4.w * gj3;
            s1 += b4.x * gj0 + b4.y * gj1 + b4.z * gj2 + b4.w * gj3;
        }
        float s = s0 + s1, ss = s0 * s0 + s1 * s1;
        float rs = wave_reduce_sum(s), rss = wave_reduce_sum(ss);
        int lane = t & 63, w = t >> 6;
        if (lane == 0) { red[w] = rs; red[8 + w] = rss; }
        __syncthreads();
        float mean = 0.f, msq = 0.f;
        #pragma unroll
        for (int i = 0; i < 4; ++i) { mean += red[i]; msq += red[8 + i]; }
        mean *= (1.0f / DD); msq *= (1.0f / DD);
        float rstd = rsqrtf(msq - mean * mean + 1e-5f);
        e[(size_t)b * DD + t]       = (s0 - mean) * rstd * de_lng[t]       + de_lnb[t];
        e[(size_t)b * DD + t + 256] = (s1 - mean) * rstd * de_lng[t + 256] + de_lnb[t + 256];
    }
}

// ---- GEMM body (BK=64, dbuf LDS, runtime mode), shared by gemm_t and dual kernels ----
template<int BM, int BN, int FM, int FN, int WGN>
__device__ __forceinline__ void gemm_body(
    const unsigned short* __restrict__ A, const unsigned short* __restrict__ W,
    const float* __restrict__ bias, const float* __restrict__ resid,
    float* __restrict__ outf, unsigned short* __restrict__ outb,
    int M, int N, int K, int mode, int bm, int bn,
    unsigned short* As, unsigned short* Ws)
{
    int t = threadIdx.x;
    int lane = t & 63, wid = t >> 6;
    int wr = wid / WGN, wc = wid % WGN;
    int l15 = lane & 15, lg = lane >> 4;
    int sr = lane >> 3;
    int sc = ((lane & 7) ^ sr) * 8;
    int ph0 = (lg ^ (l15 & 7)) * 8;
    int ph1 = ((lg + 4) ^ (l15 & 7)) * 8;

    f32x4 acc[FM][FN] = {};
    int nk = K >> 6;

    auto stage = [&](int buf, int ks) {
        int kb = ks * 64;
        #pragma unroll
        for (int i = 0; i < BM / 32; ++i) {
            int row = wid * (BM / 4) + i * 8 + sr;
            gload16(A + (size_t)(bm + row) * K + kb + sc, &As[(size_t)buf * BM * 64 + (wid * (BM / 4) + i * 8) * 64]);
        }
        #pragma unroll
        for (int i = 0; i < BN / 32; ++i) {
            int row = wid * (BN / 4) + i * 8 + sr;
            gload16(W + (size_t)(bn + row) * K + kb + sc, &Ws[(size_t)buf * BN * 64 + (wid * (BN / 4) + i * 8) * 64]);
        }
    };

    stage(0, 0);
    __syncthreads();

    int cur = 0;
    for (int ks = 0; ks < nk; ++ks) {
        if (ks + 1 < nk) stage(cur ^ 1, ks + 1);
        s16x8 af0[FM], af1[FM], wf0[FN], wf1[FN];
        #pragma unroll
        for (int mi = 0; mi < FM; ++mi) {
            int row = wr * FM * 16 + mi * 16 + l15;
            af0[mi] = *(const s16x8*)&As[(size_t)cur * BM * 64 + row * 64 + ph0];
            af1[mi] = *(const s16x8*)&As[(size_t)cur * BM * 64 + row * 64 + ph1];
        }
        #pragma unroll
        for (int ni = 0; ni < FN; ++ni) {
            int row = wc * FN * 16 + ni * 16 + l15;
            wf0[ni] = *(const s16x8*)&Ws[(size_t)cur * BN * 64 + row * 64 + ph0];
            wf1[ni] = *(const s16x8*)&Ws[(size_t)cur * BN * 64 + row * 64 + ph1];
        }
        #pragma unroll
        for (int mi = 0; mi < FM; ++mi)
            #pragma unroll
            for (int ni = 0; ni < FN; ++ni) {
                acc[mi][ni] = __builtin_amdgcn_mfma_f32_16x16x32_bf16(af0[mi], wf0[ni], acc[mi][ni], 0, 0, 0);
                acc[mi][ni] = __builtin_amdgcn_mfma_f32_16x16x32_bf16(af1[mi], wf1[ni], acc[mi][ni], 0, 0, 0);
            }
        __syncthreads();
        cur ^= 1;
    }

    int rbase = (lane >> 4) * 4;
    #pragma unroll
    for (int mi = 0; mi < FM; ++mi) {
        #pragma unroll
        for (int ni = 0; ni < FN; ++ni) {
            int n = bn + wc * FN * 16 + ni * 16 + l15;
            float bzc = (mode == 4) ? 0.f : bias[n];
            #pragma unroll
            for (int r2 = 0; r2 < 4; ++r2) {
                int m = bm + wr * FM * 16 + mi * 16 + rbase + r2;
                float v = acc[mi][ni][r2] + ((mode == 4) ? bias[m] : bzc);
                size_t o = (size_t)m * N + n;
                if (mode == 0)      outf[o] = v;
                else if (mode == 1) outb[o] = f2bf(v);
                else if (mode == 2) outf[o] = v + resid[o];
                else if (mode == 3) outb[o] = f2bf(gelu_exact(v));
                else                outb[o] = f2bf(v);
            }
        }
    }
}

// ---- standalone templated GEMM ----
template<int BM, int BN, int FM, int FN, int WGN, int MODE>
__global__ __launch_bounds__(256) void gemm_t(
    const unsigned short* __restrict__ A, const unsigned short* __restrict__ W,
    const float* __restrict__ bias, const float* __restrict__ resid,
    float* __restrict__ outf, unsigned short* __restrict__ outb,
    int M, int N, int K)
{
    __shared__ __align__(16) unsigned short As[2 * BM * 64];
    __shared__ __align__(16) unsigned short Ws[2 * BN * 64];
    gemm_body<BM, BN, FM, FN, WGN>(A, W, bias, resid, outf, outb, M, N, K, MODE,
                                   blockIdx.y * BM, blockIdx.x * BN, As, Ws);
}

// ---- dual dispatch: h0 GEMM (512 blocks) + cpe GEMM (512 blocks) ----
__global__ __launch_bounds__(256) void gemm_pre_dual(
    const unsigned short* __restrict__ x_bf, const unsigned short* __restrict__ w_in,
    const float* __restrict__ in_b, float* __restrict__ h,
    const unsigned short* __restrict__ Zb, const unsigned short* __restrict__ w_cpe,
    const float* __restrict__ cpe_b, float* __restrict__ cpe_pre)
{
    __shared__ __align__(16) unsigned short As[2 * 64 * 64];
    __shared__ __align__(16) unsigned short Ws[2 * 64 * 64];
    int id = blockIdx.x;
    if (id < 512) {
        gemm_body<64, 64, 2, 2, 2>(x_bf, w_in, in_b, nullptr, h, nullptr,
                                   MM, DD, DIN, 0, (id >> 3) * 64, (id & 7) * 64, As, Ws);
    } else {
        id -= 512;
        gemm_body<64, 64, 2, 2, 2>(Zb, w_cpe, cpe_b, nullptr, cpe_pre, nullptr,
                                   MM, DD, FEATP, 0, (id >> 3) * 64, (id & 7) * 64, As, Ws);
    }
}

// ---- dual dispatch: QK GEMM (1024 blocks) + V^T GEMM (512 blocks) ----
__global__ __launch_bounds__(256) void gemm_qkv_dual(
    const unsigned short* __restrict__ act1,
    const unsigned short* __restrict__ wqk, const float* __restrict__ qk_bias,
    unsigned short* __restrict__ qkb,
    const unsigned short* __restrict__ wv, const float* __restrict__ v_bias,
    unsigned short* __restrict__ vtb)
{
    __shared__ __align__(16) unsigned short As[2 * 64 * 64];
    __shared__ __align__(16) unsigned short Ws[2 * 64 * 64];
    int id = blockIdx.x;
    if (id < 1024) {
        gemm_body<64, 64, 2, 2, 2>(act1, wqk, qk_bias, nullptr, nullptr, qkb,
                                   MM, 1024, DD, 1, (id >> 4) * 64, (id & 15) * 64, As, Ws);
    } else {
        id -= 1024;
        gemm_body<64, 64, 2, 2, 2>(wv, act1, v_bias, nullptr, nullptr, vtb,
                                   DD, MM, DD, 4, (id >> 6) * 64, (id & 63) * 64, As, Ws);
    }
}

// ------------- MFMA flash attention: natural block order (XCD-balanced), dbuf K/V -------------
#define SK 72
#define SPB 72
__global__ __launch_bounds__(256) void attn_mfma(
    const unsigned short* __restrict__ qk, const unsigned short* __restrict__ Vt,
    const float* __restrict__ c_local, const float* __restrict__ srow,
    const int* __restrict__ lengths,
    const float* __restrict__ alpha_p,
    unsigned short* __restrict__ o)
{
    __shared__ __align__(16) unsigned short Ks[2][64 * SK];
    __shared__ __align__(16) unsigned short Vts[2][64 * SK];
    __shared__ __align__(16) unsigned short Psb[64 * SPB];

    int id = blockIdx.x;
    int q0 = (id & 15) * 64;
    int hh = (id >> 4) & 7;
    int b  = id >> 7;

    int t  = threadIdx.x;
    int lane = t & 63, w = t >> 6;
    int l15 = lane & 15, lg = lane >> 4;
    int len = lengths[b];
    int nt = (len + 63) >> 6;
    int kt0 = q0 >> 6;
    bool sink_blk = (q0 == 0);
    const float alpha = *alpha_p;

    const unsigned short* qrow = qk + (size_t)(b * LL + q0 + w * 16 + l15) * 1024 + hh * DH;
    s16x8 qf0 = *(const s16x8*)(qrow + lg * 8);
    s16x8 qf1 = *(const s16x8*)(qrow + 32 + lg * 8);
    #pragma unroll
    for (int j = 0; j < 8; ++j) {
        qf0[j] = (short)f2bf(bf2f((unsigned short)qf0[j]) * 0.125f);
        qf1[j] = (short)f2bf(bf2f((unsigned short)qf1[j]) * 0.125f);
    }

    float cm1[4], cp1[4];
    #pragma unroll
    for (int r2 = 0; r2 < 4; ++r2) {
        int qi = q0 + w * 16 + lg * 4 + r2;
        cm1[r2] = 0.f; cp1[r2] = 0.f;
        if (qi >= 1 && qi < len) {
            int src = (qi == 1 || qi == LL - 1) ? qi : qi - 1;
            cm1[r2] = alpha * c_local[(size_t)b * LL + src];
        }
        if (qi + 1 < LL && qi < len)
            cp1[r2] = alpha * c_local[(size_t)b * LL + qi + 1];
    }
    bool need_sink = (sink_blk && w == 0 && lg == 0);

    float m_run[4], l_run[4];
    f32x4 accO[4] = {};
    #pragma unroll
    for (int r2 = 0; r2 < 4; ++r2) { m_run[r2] = -1e30f; l_run[r2] = 0.f; }

    int sr = t >> 3, sc8 = (t & 7) * 8;
    const unsigned short* kbase = qk + (size_t)(b * LL) * 1024 + 512 + hh * DH;
    const unsigned short* vbase = Vt + (size_t)(hh * DH) * MM + b * LL;

    uint4 pk0 = *(const uint4*)(kbase + (size_t)sr * 1024 + sc8);
    uint4 pk1 = *(const uint4*)(kbase + (size_t)(sr + 32) * 1024 + sc8);
    uint4 pv0 = *(const uint4*)(vbase + (size_t)sr * MM + sc8);
    uint4 pv1 = *(const uint4*)(vbase + (size_t)(sr + 32) * MM + sc8);
    *(uint4*)&Ks[0][sr * SK + sc8]         = pk0;
    *(uint4*)&Ks[0][(sr + 32) * SK + sc8]  = pk1;
    *(uint4*)&Vts[0][sr * SK + sc8]        = pv0;
    *(uint4*)&Vts[0][(sr + 32) * SK + sc8] = pv1;
    __syncthreads();

    int cur = 0;
    for (int kt = 0; kt < nt; ++kt) {
        int k0 = kt * 64;
        bool pre = (kt + 1 < nt);
        if (pre) {
            int kn = k0 + 64;
            pk0 = *(const uint4*)(kbase + (size_t)(kn + sr) * 1024 + sc8);
            pk1 = *(const uint4*)(kbase + (size_t)(kn + sr + 32) * 1024 + sc8);
            pv0 = *(const uint4*)(vbase + (size_t)sr * MM + kn + sc8);
            pv1 = *(const uint4*)(vbase + (size_t)(sr + 32) * MM + kn + sc8);
        }

        f32x4 accS[4] = {};
        #pragma unroll
        for (int ct = 0; ct < 4; ++ct) {
            s16x8 kf0 = *(const s16x8*)&Ks[cur][(ct * 16 + l15) * SK + lg * 8];
            s16x8 kf1 = *(const s16x8*)&Ks[cur][(ct * 16 + l15) * SK + 32 + lg * 8];
            accS[ct] = __builtin_amdgcn_mfma_f32_16x16x32_bf16(qf0, kf0, accS[ct], 0, 0, 0);
            accS[ct] = __builtin_amdgcn_mfma_f32_16x16x32_bf16(qf1, kf1, accS[ct], 0, 0, 0);
        }

        float m4[4] = { -1e30f, -1e30f, -1e30f, -1e30f };
        bool slow = sink_blk || (kt >= kt0 - 1 && kt <= kt0 + 1) || (k0 + 64 > len);
        if (!slow) {
            #pragma unroll
            for (int ct = 0; ct < 4; ++ct)
                #pragma unroll
                for (int r2 = 0; r2 < 4; ++r2)
                    m4[r2] = fmaxf(m4[r2], accS[ct][r2]);
        } else if (k0 + 64 <= len) {
            #pragma unroll
            for (int ct = 0; ct < 4; ++ct) {
                int k = k0 + ct * 16 + l15;
                float sink_ct = need_sink ? srow[(size_t)b * LL + k] : 0.f;
                #pragma unroll
                for (int r2 = 0; r2 < 4; ++r2) {
                    int qi = q0 + w * 16 + lg * 4 + r2;
                    float v = accS[ct][r2];
                    if (k == qi - 1) v += cm1[r2];
                    else if (k == qi + 1) v += cp1[r2];
                    if (r2 == 0) v += sink_ct;
                    accS[ct][r2] = v;
                    m4[r2] = fmaxf(m4[r2], v);
                }
            }
        } else {
            #pragma unroll
            for (int ct = 0; ct < 4; ++ct) {
                int k = k0 + ct * 16 + l15;
                bool maskk = (k >= len);
                float sink_ct = need_sink ? srow[(size_t)b * LL + k] : 0.f;
                #pragma unroll
                for (int r2 = 0; r2 < 4; ++r2) {
                    int qi = q0 + w * 16 + lg * 4 + r2;
                    float v = accS[ct][r2];
                    if (k == qi - 1) v += cm1[r2];
                    else if (k == qi + 1 && !maskk) v += cp1[r2];
                    if (r2 == 0) v += sink_ct;
                    if (maskk) v -= 10000.f;
                    accS[ct][r2] = v;
                    m4[r2] = fmaxf(m4[r2], v);
                }
            }
        }

        #pragma unroll
        for (int r2 = 0; r2 < 4; ++r2) {
            #pragma unroll
            for (int msk = 1; msk < 16; msk <<= 1) m4[r2] = fmaxf(m4[r2], __shfl_xor(m4[r2], msk));
            float mnew = fmaxf(m_run[r2], m4[r2]);
            float scl = __expf(m_run[r2] - mnew);
            m_run[r2] = mnew;
            float rowsum = 0.f;
            #pragma unroll
            for (int ct = 0; ct < 4; ++ct) {
                float p = __expf(accS[ct][r2] - mnew);
                rowsum += p;
                Psb[(w * 16 + lg * 4 + r2) * SPB + ct * 16 + l15] = f2bf(p);
            }
            #pragma unroll
            for (int msk = 1; msk < 16; msk <<= 1) rowsum += __shfl_xor(rowsum, msk);
            l_run[r2] = l_run[r2] * scl + rowsum;
            #pragma unroll
            for (int dt = 0; dt < 4; ++dt) accO[dt][r2] *= scl;
        }

        #pragma unroll
        for (int kk = 0; kk < 2; ++kk) {
            s16x8 pf = *(const s16x8*)&Psb[(w * 16 + l15) * SPB + kk * 32 + lg * 8];
            #pragma unroll
            for (int dt = 0; dt < 4; ++dt) {
                s16x8 vf = *(const s16x8*)&Vts[cur][(dt * 16 + l15) * SK + kk * 32 + lg * 8];
                accO[dt] = __builtin_amdgcn_mfma_f32_16x16x32_bf16(pf, vf, accO[dt], 0, 0, 0);
            }
        }

        if (pre) {
            int nxt = cur ^ 1;
            *(uint4*)&Ks[nxt][sr * SK + sc8]         = pk0;
            *(uint4*)&Ks[nxt][(sr + 32) * SK + sc8]  = pk1;
            *(uint4*)&Vts[nxt][sr * SK + sc8]        = pv0;
            *(uint4*)&Vts[nxt][(sr + 32) * SK + sc8] = pv1;
        }
        __syncthreads();
        cur ^= 1;
    }

    #pragma unroll
    for (int r2 = 0; r2 < 4; ++r2) {
        float inv = 1.f / l_run[r2];
        int qi = q0 + w * 16 + lg * 4 + r2;
        #pragma unroll
        for (int dt = 0; dt < 4; ++dt)
            o[(size_t)(b * LL + qi) * DD + hh * DH + dt * 16 + l15] = f2bf(accO[dt][r2] * inv);
    }
}

// ------ embed epilogue: h += e + mask?0:gain*LN(cpe_pre) ------
__global__ __launch_bounds__(256) void embed_ep_kernel(
    const float* __restrict__ cpe_pre, const float* __restrict__ e,
    const int* __restrict__ lengths,
    const float* __restrict__ cpe_g, const float* __restrict__ cpe_lb,
    const float* __restrict__ gain_p, float* __restrict__ h)
{
    int row = blockIdx.x;
    int b = row >> 10, l = row & 1023;
    int t = threadIdx.x;
    __shared__ float red[16];
    const float* cp = cpe_pre + (size_t)row * DD;
    float v0 = cp[t], v1 = cp[t + 256];
    float s = v0 + v1, ss = v0 * v0 + v1 * v1;
    float rs = wave_reduce_sum(s), rss = wave_reduce_sum(ss);
    int lane = t & 63, w = t >> 6;
    if (lane == 0) { red[w] = rs; red[8 + w] = rss; }
    __syncthreads();
    float mean = 0.f, msq = 0.f;
    #pragma unroll
    for (int i = 0; i < 4; ++i) { mean += red[i]; msq += red[8 + i]; }
    mean *= (1.0f / DD); msq *= (1.0f / DD);
    float rstd = rsqrtf(msq - mean * mean + 1e-5f);
    bool maskp = (l >= lengths[b]);
    float gain = *gain_p;
    float pe0 = maskp ? 0.f : gain * ((v0 - mean) * rstd * cpe_g[t] + cpe_lb[t]);
    float pe1 = maskp ? 0.f : gain * ((v1 - mean) * rstd * cpe_g[t + 256] + cpe_lb[t + 256]);
    h[(size_t)row * DD + t]       += e[(size_t)b * DD + t] + pe0;
    h[(size_t)row * DD + t + 256] += e[(size_t)b * DD + t + 256] + pe1;
}

// ---------------- LayerNorm f32 out (final) ----------------
__global__ __launch_bounds__(256) void ln_kernel(
    const float* __restrict__ in, float* __restrict__ out,
    const float* __restrict__ g, const float* __restrict__ bta)
{
    int row = blockIdx.x; int t = threadIdx.x;
    __shared__ float red[16];
    const float* xr = in + (size_t)row * DD;
    float2 v = ((const float2*)xr)[t];
    float s = v.x + v.y, ss = v.x * v.x + v.y * v.y;
    float rs = wave_reduce_sum(s), rss = wave_reduce_sum(ss);
    int lane = t & 63, w = t >> 6;
    if (lane == 0) { red[w] = rs; red[8 + w] = rss; }
    __syncthreads();
    float mean = 0.f, msq = 0.f;
    #pragma unroll
    for (int i = 0; i < 4; ++i) { mean += red[i]; msq += red[8 + i]; }
    mean *= (1.0f / DD); msq *= (1.0f / DD);
    float rstd = rsqrtf(msq - mean * mean + 1e-5f);
    float2 gg = ((const float2*)g)[t], bb = ((const float2*)bta)[t];
    float2 o;
    o.x = (v.x - mean) * rstd * gg.x + bb.x;
    o.y = (v.y - mean) * rstd * gg.y + bb.y;
    ((float2*)(out + (size_t)row * DD))[t] = o;
}

// ---------------- LayerNorm bf16 out ----------------
__global__ __launch_bounds__(256) void ln_bf16_kernel(
    const float* __restrict__ in, unsigned short* __restrict__ out,
    const float* __restrict__ g, const float* __restrict__ bta)
{
    int row = blockIdx.x; int t = threadIdx.x;
    __shared__ float red[16];
    const float* xr = in + (size_t)row * DD;
    float2 v = ((const float2*)xr)[t];
    float s = v.x + v.y, ss = v.x * v.x + v.y * v.y;
    float rs = wave_reduce_sum(s), rss = wave_reduce_sum(ss);
    int lane = t & 63, w = t >> 6;
    if (lane == 0) { red[w] = rs; red[8 + w] = rss; }
    __syncthreads();
    float mean = 0.f, msq = 0.f;
    #pragma unroll
    for (int i = 0; i < 4; ++i) { mean += red[i]; msq += red[8 + i]; }
    mean *= (1.0f / DD); msq *= (1.0f / DD);
    float rstd = rsqrtf(msq - mean * mean + 1e-5f);
    float2 gg = ((const float2*)g)[t], bb = ((const float2*)bta)[t];
    ushort2 o;
    o.x = f2bf((v.x - mean) * rstd * gg.x + bb.x);
    o.y = f2bf((v.y - mean) * rstd * gg.y + bb.y);
    ((ushort2*)(out + (size_t)row * DD))[t] = o;
}

extern "C" void kernel_launch(void* const* d_in, const int* in_sizes, int n_in,
                              void* d_out, int out_size, void* d_ws, size_t ws_size,
                              hipStream_t stream)
{
    const float* x          = (const float*)d_in[0];
    const int*   lengths    = (const int*)  d_in[1];
    const float* input_delay= (const float*)d_in[2];
    const float* c_local    = (const float*)d_in[3];
    const float* c_sink     = (const float*)d_in[4];
    const float* in_w       = (const float*)d_in[5];
    const float* in_b       = (const float*)d_in[6];
    const float* de_w1      = (const float*)d_in[7];
    const float* de_b1      = (const float*)d_in[8];
    const float* de_w2      = (const float*)d_in[9];
    const float* de_b2      = (const float*)d_in[10];
    const float* de_ln_g    = (const float*)d_in[11];
    const float* de_ln_b    = (const float*)d_in[12];
    const float* cpe_w      = (const float*)d_in[13];
    const float* cpe_b      = (const float*)d_in[14];
    const float* cpe_ln_g   = (const float*)d_in[15];
    const float* cpe_ln_b   = (const float*)d_in[16];
    const float* gain       = (const float*)d_in[17];
    const float* alpha      = (const float*)d_in[18];
    const float* beta       = (const float*)d_in[19];
    const float* floorp     = (const float*)d_in[20];
    const float* gammap     = (const float*)d_in[21];
    const float* inproj_w   = (const float*)d_in[22];
    const float* inproj_b   = (const float*)d_in[23];
    const float* outproj_w  = (const float*)d_in[24];
    const float* outproj_b  = (const float*)d_in[25];
    const float* ln1_g      = (const float*)d_in[26];
    const float* ln1_b      = (const float*)d_in[27];
    const float* ln2_g      = (const float*)d_in[28];
    const float* ln2_b      = (const float*)d_in[29];
    const float* ff_w1      = (const float*)d_in[30];
    const float* ff_b1      = (const float*)d_in[31];
    const float* ff_w2      = (const float*)d_in[32];
    const float* ff_b2      = (const float*)d_in[33];
    const float* out_ln_g   = (const float*)d_in[34];
    const float* out_ln_b   = (const float*)d_in[35];

    char* base = (char*)d_ws;
    float* h            = (float*)base;                               // 8 MB
    unsigned short* act1 = (unsigned short*)(base + 8u*1024*1024);    // 4 MB
    char* bigb          = base + 12u*1024*1024;                       // 16 MB shared region
    unsigned short* qkb  = (unsigned short*)bigb;                     // 8 MB (attn phase: Q,K)
    unsigned short* vtb  = (unsigned short*)(bigb + 12u*1024*1024);   // 4 MB (attn phase: V^T [512][4096])
    unsigned short* ffb  = (unsigned short*)bigb;                     // 16 MB (FF phase)
    unsigned short* Zb   = (unsigned short*)bigb;                     // 4.7 MB (embed phase)
    unsigned short* x_bf = (unsigned short*)(bigb + 5u*1024*1024);    // 0.5 MB
    float* cpe_pre       = (float*)(bigb + 8u*1024*1024);             // 8 MB
    unsigned short* w_inproj  = (unsigned short*)(base + 28u*1024*1024);
    unsigned short* w_outproj = w_inproj  + (size_t)3*1536*512;
    unsigned short* w_ff1     = w_outproj + (size_t)3*512*512;
    unsigned short* w_ff2     = w_ff1     + (size_t)3*2048*512;
    unsigned short* w_in      = w_ff2     + (size_t)3*512*2048;
    unsigned short* w_cpe     = w_in      + (size_t)512*64;
    float* e                  = (float*)(w_cpe + (size_t)512*FEATP);
    float* srow               = e + (size_t)BB*DD;

    // fused prologue: PE/z (1024) | vectorized prep (2048) | delay (4)
    prologue_kernel<<<LL + 2048 + BB, 256, 0, stream>>>(
        c_local, c_sink, lengths, beta, floorp, gammap, Zb, srow,
        x, inproj_w, outproj_w, ff_w1, ff_w2, in_w, cpe_w,
        x_bf, w_inproj, w_outproj, w_ff1, w_ff2, w_in, w_cpe,
        input_delay, de_w1, de_b1, de_w2, de_b2, de_ln_g, de_ln_b, e);

    // h0 GEMM + cpe GEMM fused into one dispatch (independent)
    gemm_pre_dual<<<1024, 256, 0, stream>>>(x_bf, w_in, in_b, h, Zb, w_cpe, cpe_b, cpe_pre);
    embed_ep_kernel<<<MM, 256, 0, stream>>>(cpe_pre, e, lengths, cpe_ln_g, cpe_ln_b, gain, h);

    for (int i = 0; i < NLAYER; ++i) {
        const unsigned short* wqk = w_inproj + (size_t)i * 1536 * 512;          // Q,K rows [0,1024)
        const unsigned short* wv  = wqk + (size_t)1024 * 512;                   // V rows [1024,1536)
        ln_bf16_kernel<<<MM, 256, 0, stream>>>(h, act1, ln1_g + (size_t)i * DD, ln1_b + (size_t)i * DD);
        gemm_qkv_dual<<<1536, 256, 0, stream>>>(act1, wqk, inproj_b + (size_t)i * 1536,
                                                qkb, wv, inproj_b + (size_t)i * 1536 + 1024, vtb);
        attn_mfma<<<512, 256, 0, stream>>>(qkb, vtb, c_local, srow, lengths, alpha, act1);
        gemm_t<64, 64, 2, 2, 2, 2><<<dim3(DD / 64, MM / 64), 256, 0, stream>>>(
            act1, w_outproj + (size_t)i * 512 * 512, outproj_b + (size_t)i * DD,
            h, h, nullptr, MM, DD, DD);
        ln_bf16_kernel<<<MM, 256, 0, stream>>>(h, act1, ln2_g + (size_t)i * DD, ln2_b + (size_t)i * DD);
        gemm_t<128, 128, 4, 4, 2, 3><<<dim3(DFF / 128, MM / 128), 256, 0, stream>>>(
            act1, w_ff1 + (size_t)i * 2048 * 512, ff_b1 + (size_t)i * DFF,
            nullptr, nullptr, ffb, MM, DFF, DD);
        gemm_t<64, 64, 2, 2, 2, 2><<<dim3(DD / 64, MM / 64), 256, 0, stream>>>(
            ffb, w_ff2 + (size_t)i * 512 * 2048, ff_b2 + (size_t)i * DD,
            h, h, nullptr, MM, DD, DFF);
    }
    ln_kernel<<<MM, 256, 0, stream>>>(h, (float*)d_out, out_ln_g, out_ln_b);
}